// Round 4
// baseline (11796.066 us; speedup 1.0000x reference)
//
#include <hip/hip_runtime.h>
#include <stdint.h>

#define SEQ   1024
#define BATCH 32
#define HID   512
#define G3    1536
#define NW    32          // rec workgroups per direction
#define JPW   16          // hidden units owned per rec WG
#define THREADS 256       // 4 waves: (kh 0..1) x (mi 0..1)
#define FSTR  256         // chunk-flag spacing in ints (1KB)
#define CSTR  64          // prodcnt spacing in ints (256B)
#define CH    16          // steps per Xi chunk
#define NCH   64          // chunks per layer (CH*NCH == SEQ)
#define NG    192         // gate-row groups of 16 (= 3072/16), ng = dir*96+g*32+wg
#define NPROD 192         // producer WGs
#define SPIN_MAX 65536    // spin bail-out (~30ms worst case); legit waits <<100us

typedef __attribute__((ext_vector_type(8))) short  short8;
typedef __attribute__((ext_vector_type(4))) float  f32x4;
typedef __attribute__((ext_vector_type(4))) unsigned short us4;
typedef unsigned long long ull;

__device__ __forceinline__ unsigned short f2bf(float f) {
  union { float f; unsigned int u; } v; v.f = f;
  unsigned int u = v.u;
  return (unsigned short)((u + 0x7FFFu + ((u >> 16) & 1u)) >> 16);
}
__device__ __forceinline__ float bf2f(unsigned short u) {
  union { unsigned int i; float f; } v; v.i = ((unsigned int)u) << 16; return v.f;
}
__device__ __forceinline__ short8 pack8(const float* __restrict__ p) {
  short8 o;
#pragma unroll
  for (int i = 0; i < 8; i++) o[i] = (short)f2bf(p[i]);
  return o;
}
__device__ __forceinline__ f32x4 mfma16(short8 a, short8 b, f32x4 c) {
  return __builtin_amdgcn_mfma_f32_16x16x32_bf16(a, b, c, 0, 0, 0);
}

// fp32 W [3072][K] -> bf16 B-fragment chunks [ng][kc][64 lane] x 16B
__global__ void cvt_wb(const float* __restrict__ w, short8* __restrict__ out, int kcx, int nc) {
  int c = blockIdx.x * blockDim.x + threadIdx.x;
  if (c >= nc) return;
  int lane = c & 63, r = c >> 6;     // r = ng*kcx + kc
  int kc = r % kcx, ng = r / kcx;
  int n   = ng * 16 + (lane & 15);
  int col = kc * 32 + (lane >> 4) * 8;
  int K = kcx * 32;
  out[c] = pack8(w + (size_t)n * K + col);
}

// One dispatch per layer, grid=256, 256 threads (4 waves).
// blk%8==0 -> rec dir0 (wg=blk>>3); blk%8==1 -> rec dir1; blk%8>=2 -> producers.
// ALL cross-WG data via sc0+sc1 (LLC) -- the proven-correct baseline protocol.
// (The sc0-only "XCD fast path" from rounds 1-3 is removed: it deadlocked /
// corrupted h when placement assumptions failed; no fast mode anywhere.)
// Per-step flags are PACKED: 32 ints in one 128B line per direction, so the
// spin is a single coalesced 32-lane load (1 LLC transaction) instead of a
// 32-line gather. Chunk flags (producer pacing) stay spread at FSTR.
// Rec wave roles: wave = kh*2 + mi (kh = K-half, mi = batch half). Each wave
// reads a DISJOINT 8KB of h (dedup: 32KB/WG/step vs 96KB in the 9947us
// baseline) and computes partials for all 3 gates; fp32 cross-wave reduce in
// LDS. Waves 1..3 carry Xi gate (wave-1) for both mi halves, hoisted before
// the flag spin when the chunk was already validated (sl != 0).
template<int KCX, bool WRITE_Y>
__global__ __launch_bounds__(THREADS, 1) void gru_mega(
    const void* __restrict__ Ain,      // KCX==8: fp32 x [T][32][256]; else short8 [T][2][KCX][64]
    short8* __restrict__ yout,         // [T][2][32][64] chunks (or null)
    const short8* __restrict__ wb,     // [NG][KCX][64] B-fragments
    const float* __restrict__ whh,     // [2][G3][HID]
    const float* __restrict__ bih,     // [3072]
    const float* __restrict__ bhh,     // [3072]
    us4* __restrict__ Xic,             // [2 slot][CH][NG][2 mi][64]
    short8* __restrict__ hbuf,         // [2 dir][2 par][2 mi][16 kc][64] chunks
    int* __restrict__ pflags,          // [2 dir][32] per-step flags, 1 line/dir
    int* __restrict__ cflags,          // [2][NW][FSTR] per-chunk (producer pacing)
    int* __restrict__ prodcnt,         // [NCH][CSTR]
    float* __restrict__ hout)          // [2][BATCH][HID] slice of d_out
{
  __shared__ f32x4 pbuf[768];    // [2 kh][3 g][2 mi][4 quad][16 j] f32x4 = 12KB
  __shared__ ull   xbuf3[384];   // [3 g][2 mi][64 lane] raw Xi bf16x4 = 3KB

  const int tid  = threadIdx.x;
  const int lane = tid & 63;
  const int wave = tid >> 6;
  const int quad = lane >> 4;
  const int l15  = lane & 15;
  const int bx   = blockIdx.x;
  const int sub  = bx & 7;

  if (sub >= 2) {
    // ================= producer =================
    const int p    = (bx >> 3) * 6 + (sub - 2);   // 0..191
    const int tg   = p & 15;           // sl within chunk (CH==16)
    const int ngg  = p >> 4;           // 0..11 -> ng range [ngg*16, ngg*16+16)
    const int dirp = (ngg >= 6) ? 1 : 0;
    int* fl = cflags + dirp * NW * FSTR;

    for (int c = 0; c < NCH; c++) {
      const int tgt = (c >= 2) ? CH * (c - 1) : 0;
      if (wave == 0) {
        int it = 0;
        while (true) {
          int v = (lane < NW)
                    ? __hip_atomic_load(&fl[lane * FSTR], __ATOMIC_RELAXED, __HIP_MEMORY_SCOPE_AGENT)
                    : tgt;
          if (__all(v >= tgt)) break;
          if (++it > SPIN_MAX) break;            // bail (diagnostic insurance)
          __builtin_amdgcn_s_sleep(16);
        }
      }
      __syncthreads();
      const int sl = tg;
      const int s  = c * CH + sl;
      const int t  = dirp ? (SEQ - 1 - s) : s;
      for (int mi2 = 0; mi2 < 2; mi2++) {
        short8 a[KCX];
        if constexpr (KCX == 8) {
          const float* xr = (const float*)Ain + ((size_t)t * 32 + mi2 * 16 + l15) * 256 + quad * 8;
#pragma unroll
          for (int kc = 0; kc < KCX; kc++) a[kc] = pack8(xr + kc * 32);
        } else {
          const short8* ap = (const short8*)Ain + ((size_t)(t * 2 + mi2) * KCX) * 64 + lane;
#pragma unroll
          for (int kc = 0; kc < KCX; kc++) a[kc] = ap[kc * 64];
        }
        for (int ng = ngg * 16 + wave; ng < ngg * 16 + 16; ng += 4) {
          const short8* bp = wb + (size_t)ng * KCX * 64 + lane;
          f32x4 ac0 = (f32x4){0.f, 0.f, 0.f, 0.f};
          f32x4 ac1 = (f32x4){0.f, 0.f, 0.f, 0.f};
#pragma unroll
          for (int kc = 0; kc < KCX; kc += 2) {
            ac0 = mfma16(a[kc],     bp[kc * 64],       ac0);
            ac1 = mfma16(a[kc + 1], bp[(kc + 1) * 64], ac1);
          }
          const int n  = ng * 16 + l15;
          const int gg = (ng % 96) >> 5;                    // 0=r,1=z,2=n
          const float bias = bih[n] + (gg < 2 ? bhh[n] : 0.f);
          us4 o;
#pragma unroll
          for (int r = 0; r < 4; r++) o[r] = f2bf(ac0[r] + ac1[r] + bias);
          us4* dst = Xic + ((((size_t)(c & 1)) * CH + sl) * NG + ng) * 128 + mi2 * 64 + lane;
          asm volatile("global_store_dwordx2 %0, %1, off sc0 sc1" :: "v"(dst), "v"(o) : "memory");
        }
      }
      asm volatile("s_waitcnt vmcnt(0)" ::: "memory");
      __syncthreads();
      if (tid == 0)
        __hip_atomic_fetch_add(&prodcnt[c * CSTR], 1, __ATOMIC_RELAXED, __HIP_MEMORY_SCOPE_AGENT);
    }
    return;
  }

  // ================= recurrence =================
  const int mi  = wave & 1;
  const int kh  = wave >> 1;          // K-half: kc = kh*8 .. kh*8+7
  const int dir = sub;                // 0 or 1
  const int wg  = bx >> 3;            // 0..31
  const int j0  = wg * JPW;
  const bool rev = (dir == 1);

  // W_hh B-fragments: all 3 gates, my K-half. 24 frags = 96 VGPRs.
  short8 wh[3][8];
  {
    const float* pwd = whh + (size_t)dir * G3 * HID;
#pragma unroll
    for (int g = 0; g < 3; g++) {
      const float* pw = pwd + (size_t)(g * HID + j0 + l15) * HID + quad * 8;
#pragma unroll
      for (int c = 0; c < 8; c++) wh[g][c] = pack8(pw + (kh * 8 + c) * 32);
    }
  }
  // gate-thread constants/state: tid<128 -> (gmi,gq,gj) owns batches gmi*16+gq*4+r, hidden j0+gj
  const float bhn = bhh[dir * G3 + 2 * HID + j0 + (tid & 15)];   // bhh gate-n
  f32x4 hreg = (f32x4){0.f, 0.f, 0.f, 0.f};

  int* pfl = pflags + dir * 32;                        // one 128B line
  int* cfl = cflags + dir * NW * FSTR;
  char* hb = (char*)(hbuf + (size_t)dir * 2 * 2048);   // [2 par][32KB]

  for (int s = 0; s < SEQ; s++) {
    const int t  = rev ? (SEQ - 1 - s) : s;
    const int c  = s >> 4;
    const int sl = s & 15;

    // Xi: wave w>=1 carries gate (w-1), both mi halves (mi stride = 512B).
    const int xig = (wave >= 1) ? (wave - 1) : 0;
    const char* xp = (const char*)Xic
        + (((((size_t)(c & 1)) * CH + sl) * NG + (dir * 96 + xig * 32 + wg)) * 128 + lane) * 8;
    ull xi0 = 0, xi1 = 0;
    if (wave >= 1 && sl != 0)   // chunk validated at its sl==0 step: pre-spin load OK
      asm volatile(
          "global_load_dwordx2 %0, %2, off sc0 sc1\n\t"
          "global_load_dwordx2 %1, %2, off offset:512 sc0 sc1\n\t"
          "s_waitcnt vmcnt(0)"
          : "=&v"(xi0), "=&v"(xi1) : "v"(xp) : "memory");

    if (wave == 0) {
      int* fp = pfl + (lane & 31);     // coalesced: one 128B line per poll
      int it = 0;
      while (true) {
        int v = s;
        if (s > 0)
          asm volatile("global_load_dword %0, %1, off sc0 sc1\n\ts_waitcnt vmcnt(0)"
                       : "=v"(v) : "v"(fp) : "memory");
        bool ok = __all(v >= s);
        if (ok && sl == 0) {
          int cnt = __hip_atomic_load(&prodcnt[c * CSTR], __ATOMIC_RELAXED, __HIP_MEMORY_SCOPE_AGENT);
          ok = (cnt >= NPROD);
        }
        if (ok) break;
        if (++it > SPIN_MAX) break;                    // bail (diagnostic insurance)
        __builtin_amdgcn_s_sleep(1);
      }
    }
    __syncthreads();
    if (wave >= 1 && sl == 0)   // slot only valid after prodcnt gate
      asm volatile(
          "global_load_dwordx2 %0, %2, off sc0 sc1\n\t"
          "global_load_dwordx2 %1, %2, off offset:512 sc0 sc1\n\t"
          "s_waitcnt vmcnt(0)"
          : "=&v"(xi0), "=&v"(xi1) : "v"(xp) : "memory");

    // ---- h projection partials: my (mi, K-half) slice, all 3 gates ----
    f32x4 p0 = (f32x4){0.f, 0.f, 0.f, 0.f};
    f32x4 p1 = (f32x4){0.f, 0.f, 0.f, 0.f};
    f32x4 p2 = (f32x4){0.f, 0.f, 0.f, 0.f};
    if (s > 0) {
      const char* hp = hb + (size_t)((s - 1) & 1) * 32768 + (size_t)mi * 16384
                     + (size_t)kh * 8192 + (size_t)lane * 16;
      short8 a0, a1, a2, a3, a4, a5, a6, a7;
      asm volatile(
          "global_load_dwordx4 %0, %8, off sc0 sc1\n\t"
          "global_load_dwordx4 %1, %8, off offset:1024 sc0 sc1\n\t"
          "global_load_dwordx4 %2, %8, off offset:2048 sc0 sc1\n\t"
          "global_load_dwordx4 %3, %8, off offset:3072 sc0 sc1\n\t"
          "global_load_dwordx4 %4, %9, off sc0 sc1\n\t"
          "global_load_dwordx4 %5, %9, off offset:1024 sc0 sc1\n\t"
          "global_load_dwordx4 %6, %9, off offset:2048 sc0 sc1\n\t"
          "global_load_dwordx4 %7, %9, off offset:3072 sc0 sc1\n\t"
          "s_waitcnt vmcnt(0)"
          : "=&v"(a0), "=&v"(a1), "=&v"(a2), "=&v"(a3),
            "=&v"(a4), "=&v"(a5), "=&v"(a6), "=&v"(a7)
          : "v"(hp), "v"(hp + 4096) : "memory");
      p0 = mfma16(a0, wh[0][0], p0); p1 = mfma16(a0, wh[1][0], p1); p2 = mfma16(a0, wh[2][0], p2);
      p0 = mfma16(a1, wh[0][1], p0); p1 = mfma16(a1, wh[1][1], p1); p2 = mfma16(a1, wh[2][1], p2);
      p0 = mfma16(a2, wh[0][2], p0); p1 = mfma16(a2, wh[1][2], p1); p2 = mfma16(a2, wh[2][2], p2);
      p0 = mfma16(a3, wh[0][3], p0); p1 = mfma16(a3, wh[1][3], p1); p2 = mfma16(a3, wh[2][3], p2);
      p0 = mfma16(a4, wh[0][4], p0); p1 = mfma16(a4, wh[1][4], p1); p2 = mfma16(a4, wh[2][4], p2);
      p0 = mfma16(a5, wh[0][5], p0); p1 = mfma16(a5, wh[1][5], p1); p2 = mfma16(a5, wh[2][5], p2);
      p0 = mfma16(a6, wh[0][6], p0); p1 = mfma16(a6, wh[1][6], p1); p2 = mfma16(a6, wh[2][6], p2);
      p0 = mfma16(a7, wh[0][7], p0); p1 = mfma16(a7, wh[1][7], p1); p2 = mfma16(a7, wh[2][7], p2);
    }

    // partial dump + Xi dump (conflict-free b128 / b64)
    {
      const int idx0 = mi * 64 + quad * 16 + l15;
      pbuf[kh * 384 + idx0]       = p0;
      pbuf[kh * 384 + 128 + idx0] = p1;
      pbuf[kh * 384 + 256 + idx0] = p2;
      if (wave >= 1) {
        xbuf3[xig * 128 + lane]      = xi0;   // mi = 0
        xbuf3[xig * 128 + 64 + lane] = xi1;   // mi = 1
      }
    }
    __syncthreads();

    // ---- gates + state + publish: 128 threads, 4 batch rows each ----
    if (tid < 128) {
      const int gmi = tid >> 6, gq = (tid >> 4) & 3, gj = tid & 15;
      const int kg  = j0 + gj;
      const int rb  = gmi * 64 + gq * 16 + gj;
      f32x4 s0 = pbuf[rb]       + pbuf[384 + rb];
      f32x4 s1 = pbuf[128 + rb] + pbuf[512 + rb];
      f32x4 s2 = pbuf[256 + rb] + pbuf[640 + rb];
      const ull xr_ = xbuf3[rb];
      const ull xz_ = xbuf3[128 + rb];
      const ull xn_ = xbuf3[256 + rb];
      f32x4 hnew;
#pragma unroll
      for (int r = 0; r < 4; r++) {
        float rr  = 1.f / (1.f + __expf(-(s0[r] + bf2f((unsigned short)(xr_ >> (16 * r))))));
        float zz  = 1.f / (1.f + __expf(-(s1[r] + bf2f((unsigned short)(xz_ >> (16 * r))))));
        float px  = bf2f((unsigned short)(xn_ >> (16 * r)));
        float a2v = px + rr * (s2[r] + bhn);
        float ex  = __expf(2.f * a2v);
        float nn  = 1.f - 2.f / (ex + 1.f);        // tanh(a2v)
        hnew[r] = (1.f - zz) * nn + zz * hreg[r];
      }
      hreg = hnew;
      const int kc = kg >> 5;
      const int qq = (kg >> 3) & 3;
      char* pdst = hb + (size_t)(s & 1) * 32768 + (size_t)gmi * 16384
                 + (size_t)kc * 1024 + (size_t)(qq * 16 + gq * 4) * 16 + (size_t)(kg & 7) * 2;
#pragma unroll
      for (int r = 0; r < 4; r++) {
        unsigned int uv = (unsigned int)f2bf(hnew[r]);
        asm volatile("global_store_short %0, %1, off sc0 sc1" :: "v"(pdst + r * 16), "v"(uv) : "memory");
      }
      if (WRITE_Y) {
        char* yb = (char*)yout
            + ((((size_t)(t * 2 + gmi)) * 32 + (dir << 4) + kc) * 64 + qq * 16 + gq * 4) * 16
            + (size_t)(kg & 7) * 2;
#pragma unroll
        for (int r = 0; r < 4; r++)
          *(unsigned short*)(yb + r * 16) = f2bf(hnew[r]);
      }
      if (s == SEQ - 1) {
#pragma unroll
        for (int r = 0; r < 4; r++)
          hout[((size_t)dir * 32 + gmi * 16 + gq * 4 + r) * HID + kg] = hnew[r];
      }
    }
    asm volatile("s_waitcnt vmcnt(0)" ::: "memory");   // drain publish stores
    __syncthreads();
    if (tid == 0) {
      const int fv = s + 1;
      int* fpd = pfl + wg;
      asm volatile("global_store_dword %0, %1, off sc0 sc1" :: "v"(fpd), "v"(fv) : "memory");
      if (sl == 15)   // chunk flag for producers
        __hip_atomic_store(&cfl[wg * FSTR], fv, __ATOMIC_RELAXED, __HIP_MEMORY_SCOPE_AGENT);
    }
  }
}

extern "C" void kernel_launch(void* const* d_in, const int* in_sizes, int n_in,
                              void* d_out, int out_size, void* d_ws, size_t ws_size,
                              hipStream_t stream)
{
  const float* x       = (const float*)d_in[0];
  const float* w_ih_l0 = (const float*)d_in[1];
  const float* w_hh_l0 = (const float*)d_in[2];
  const float* b_ih_l0 = (const float*)d_in[3];
  const float* b_hh_l0 = (const float*)d_in[4];
  const float* w_ih_lr = (const float*)d_in[5];
  const float* w_hh_lr = (const float*)d_in[6];
  const float* b_ih_lr = (const float*)d_in[7];
  const float* b_hh_lr = (const float*)d_in[8];
  float* out = (float*)d_out;

  char* ws = (char*)d_ws;
  size_t off = 0;
  auto alloc = [&](size_t bytes) {
    char* p = ws + off;
    off += (bytes + 255) & ~(size_t)255;
    return p;
  };
  short8* y0   = (short8*)alloc((size_t)SEQ * 2 * 32 * 64 * 16);   // 64 MB
  short8* y1   = (short8*)alloc((size_t)SEQ * 2 * 32 * 64 * 16);   // 64 MB
  short8* wb   = (short8*)alloc((size_t)NG * 32 * 64 * 16);        // 6 MB
  short8* hbuf = (short8*)alloc((size_t)2 * 2 * 2048 * 16);        // 128 KB
  int*    pflags  = (int*)alloc((size_t)3 * 64 * 4);               // 768 B (1 line/dir/layer)
  int*    cflags  = (int*)alloc((size_t)3 * 2 * NW * FSTR * 4);    // 192 KB
  int*    prodcnt = (int*)alloc((size_t)3 * NCH * CSTR * 4);       // 48 KB
  us4*    Xic  = (us4*)alloc((size_t)2 * CH * NG * 2 * 64 * 8);    // 6 MB
  // total ~140.4 MiB < proven-safe 151 MB

  hipMemsetAsync(pflags,  0, (size_t)3 * 64 * 4, stream);
  hipMemsetAsync(cflags,  0, (size_t)3 * 2 * NW * FSTR * 4, stream);
  hipMemsetAsync(prodcnt, 0, (size_t)3 * NCH * CSTR * 4, stream);

  // ---- layer 0 (K=256, fp32 x read directly by producers) ----
  {
    int nc = NG * 8 * 64;
    cvt_wb<<<(nc + 255) / 256, 256, 0, stream>>>(w_ih_l0, wb, 8, nc);
    gru_mega<8, true><<<256, THREADS, 0, stream>>>(
        x, y0, wb, w_hh_l0, b_ih_l0, b_hh_l0, Xic, hbuf,
        pflags, cflags, prodcnt, out);
  }
  // ---- layer 1 ----
  {
    int nc = NG * 32 * 64;
    cvt_wb<<<(nc + 255) / 256, 256, 0, stream>>>(w_ih_lr, wb, 32, nc);
    gru_mega<32, true><<<256, THREADS, 0, stream>>>(
        y0, y1, wb, w_hh_lr, b_ih_lr, b_hh_lr, Xic, hbuf,
        pflags + 64, cflags + 2 * NW * FSTR,
        prodcnt + NCH * CSTR, out + 2 * BATCH * HID);
  }
  // ---- layer 2 ----
  {
    int nc = NG * 32 * 64;
    cvt_wb<<<(nc + 255) / 256, 256, 0, stream>>>(w_ih_lr + (size_t)2 * G3 * 1024, wb, 32, nc);
    gru_mega<32, false><<<256, THREADS, 0, stream>>>(
        y1, nullptr, wb, w_hh_lr + (size_t)2 * G3 * HID,
        b_ih_lr + 2 * G3, b_hh_lr + 2 * G3, Xic, hbuf,
        pflags + 128, cflags + 4 * NW * FSTR,
        prodcnt + 2 * NCH * CSTR, out + 4 * BATCH * HID);
  }
}

// Round 5
// 11006.600 us; speedup vs baseline: 1.0717x; 1.0717x over previous
//
#include <hip/hip_runtime.h>
#include <stdint.h>

#define SEQ   1024
#define BATCH 32
#define HID   512
#define G3    1536
#define NW    32          // rec workgroups per direction
#define JPW   16          // hidden units owned per rec WG
#define THREADS 256       // 4 waves: (kh 0..1) x (mi 0..1)
#define FSTR  256         // flag spacing in ints (1KB) -- one LLC line per flag
#define CSTR  64          // prodcnt spacing in ints (256B)
#define CH    16          // steps per Xi chunk
#define NCH   64          // chunks per layer (CH*NCH == SEQ)
#define NG    192         // gate-row groups of 16 (= 3072/16), ng = dir*96+g*32+wg
#define NPROD 192         // producer WGs
#define SPIN_MAX 65536    // spin bail-out; legit waits <<100us

typedef __attribute__((ext_vector_type(8))) short  short8;
typedef __attribute__((ext_vector_type(4))) float  f32x4;
typedef __attribute__((ext_vector_type(4))) unsigned short us4;
typedef unsigned long long ull;

__device__ __forceinline__ unsigned short f2bf(float f) {
  union { float f; unsigned int u; } v; v.f = f;
  unsigned int u = v.u;
  return (unsigned short)((u + 0x7FFFu + ((u >> 16) & 1u)) >> 16);
}
__device__ __forceinline__ float bf2f(unsigned short u) {
  union { unsigned int i; float f; } v; v.i = ((unsigned int)u) << 16; return v.f;
}
__device__ __forceinline__ short8 pack8(const float* __restrict__ p) {
  short8 o;
#pragma unroll
  for (int i = 0; i < 8; i++) o[i] = (short)f2bf(p[i]);
  return o;
}
__device__ __forceinline__ f32x4 mfma16(short8 a, short8 b, f32x4 c) {
  return __builtin_amdgcn_mfma_f32_16x16x32_bf16(a, b, c, 0, 0, 0);
}

// fp32 W [3072][K] -> bf16 B-fragment chunks [ng][kc][64 lane] x 16B
__global__ void cvt_wb(const float* __restrict__ w, short8* __restrict__ out, int kcx, int nc) {
  int c = blockIdx.x * blockDim.x + threadIdx.x;
  if (c >= nc) return;
  int lane = c & 63, r = c >> 6;     // r = ng*kcx + kc
  int kc = r % kcx, ng = r / kcx;
  int n   = ng * 16 + (lane & 15);
  int col = kc * 32 + (lane >> 4) * 8;
  int K = kcx * 32;
  out[c] = pack8(w + (size_t)n * K + col);
}

// One dispatch per layer, grid=256, 256 threads (4 waves).
// blk%8==0 -> rec dir0 (wg=blk>>3); blk%8==1 -> rec dir1; blk%8>=2 -> producers.
// ALL cross-WG traffic via the PROVEN baseline protocol: sc0+sc1 data stores,
// per-step flags SPREAD one per LLC line (packed-line flags in round 4 cost
// ~+900cy/step of LLC bank serialization -- reverted), atomic agent-scope
// load/store for flags. Kept from the restructure: (a) h-load dedup -- each
// wave reads a DISJOINT 8KB K-half (32KB/WG/step vs 96KB baseline, FETCH
// -23%), computing partials for all 3 gates, fp32 reduce via LDS; (b) Xi
// hoisted before the flag spin on already-validated chunks (sl != 0).
// Gate phase: baseline-exact 256 threads x 2 elems, single dword publish.
template<int KCX, bool WRITE_Y>
__global__ __launch_bounds__(THREADS, 1) void gru_mega(
    const void* __restrict__ Ain,      // KCX==8: fp32 x [T][32][256]; else short8 [T][2][KCX][64]
    short8* __restrict__ yout,         // [T][2][32][64] chunks (or null)
    const short8* __restrict__ wb,     // [NG][KCX][64] B-fragments
    const float* __restrict__ whh,     // [2][G3][HID]
    const float* __restrict__ bih,     // [3072]
    const float* __restrict__ bhh,     // [3072]
    us4* __restrict__ Xic,             // [2 slot][CH][NG][2 mi][64]
    short8* __restrict__ hbuf,         // [2 dir][2 par][2 mi][16 kc][64] chunks
    int* __restrict__ flags,           // [2][NW][FSTR] per-step
    int* __restrict__ cflags,          // [2][NW][FSTR] per-chunk (producer pacing)
    int* __restrict__ prodcnt,         // [NCH][CSTR]
    float* __restrict__ hout)          // [2][BATCH][HID] slice of d_out
{
  __shared__ f32x4 pbuf[768];    // [2 kh][3 g][2 mi][4 quad][16 j] f32x4 = 12KB
  __shared__ ull   xbuf3[384];   // [3 g][2 mi][64 lane] raw Xi bf16x4 = 3KB

  const int tid  = threadIdx.x;
  const int lane = tid & 63;
  const int wave = tid >> 6;
  const int quad = lane >> 4;
  const int l15  = lane & 15;
  const int bx   = blockIdx.x;
  const int sub  = bx & 7;

  if (sub >= 2) {
    // ================= producer =================
    const int p    = (bx >> 3) * 6 + (sub - 2);   // 0..191
    const int tg   = p & 15;           // sl within chunk (CH==16)
    const int ngg  = p >> 4;           // 0..11 -> ng range [ngg*16, ngg*16+16)
    const int dirp = (ngg >= 6) ? 1 : 0;
    int* fl = cflags + dirp * NW * FSTR;

    for (int c = 0; c < NCH; c++) {
      const int tgt = (c >= 2) ? CH * (c - 1) : 0;
      if (wave == 0) {
        int it = 0;
        while (true) {
          int v = (lane < NW)
                    ? __hip_atomic_load(&fl[lane * FSTR], __ATOMIC_RELAXED, __HIP_MEMORY_SCOPE_AGENT)
                    : tgt;
          if (__all(v >= tgt)) break;
          if (++it > SPIN_MAX) break;            // bail (diagnostic insurance)
          __builtin_amdgcn_s_sleep(16);
        }
      }
      __syncthreads();
      const int sl = tg;
      const int s  = c * CH + sl;
      const int t  = dirp ? (SEQ - 1 - s) : s;
      for (int mi2 = 0; mi2 < 2; mi2++) {
        short8 a[KCX];
        if constexpr (KCX == 8) {
          const float* xr = (const float*)Ain + ((size_t)t * 32 + mi2 * 16 + l15) * 256 + quad * 8;
#pragma unroll
          for (int kc = 0; kc < KCX; kc++) a[kc] = pack8(xr + kc * 32);
        } else {
          const short8* ap = (const short8*)Ain + ((size_t)(t * 2 + mi2) * KCX) * 64 + lane;
#pragma unroll
          for (int kc = 0; kc < KCX; kc++) a[kc] = ap[kc * 64];
        }
        for (int ng = ngg * 16 + wave; ng < ngg * 16 + 16; ng += 4) {
          const short8* bp = wb + (size_t)ng * KCX * 64 + lane;
          f32x4 ac0 = (f32x4){0.f, 0.f, 0.f, 0.f};
          f32x4 ac1 = (f32x4){0.f, 0.f, 0.f, 0.f};
#pragma unroll
          for (int kc = 0; kc < KCX; kc += 2) {
            ac0 = mfma16(a[kc],     bp[kc * 64],       ac0);
            ac1 = mfma16(a[kc + 1], bp[(kc + 1) * 64], ac1);
          }
          const int n  = ng * 16 + l15;
          const int gg = (ng % 96) >> 5;                    // 0=r,1=z,2=n
          const float bias = bih[n] + (gg < 2 ? bhh[n] : 0.f);
          us4 o;
#pragma unroll
          for (int r = 0; r < 4; r++) o[r] = f2bf(ac0[r] + ac1[r] + bias);
          us4* dst = Xic + ((((size_t)(c & 1)) * CH + sl) * NG + ng) * 128 + mi2 * 64 + lane;
          asm volatile("global_store_dwordx2 %0, %1, off sc0 sc1" :: "v"(dst), "v"(o) : "memory");
        }
      }
      asm volatile("s_waitcnt vmcnt(0)" ::: "memory");
      __syncthreads();
      if (tid == 0)
        __hip_atomic_fetch_add(&prodcnt[c * CSTR], 1, __ATOMIC_RELAXED, __HIP_MEMORY_SCOPE_AGENT);
    }
    return;
  }

  // ================= recurrence =================
  const int mi  = wave & 1;
  const int kh  = wave >> 1;          // K-half: kc = kh*8 .. kh*8+7
  const int dir = sub;                // 0 or 1
  const int wg  = bx >> 3;            // 0..31
  const int j0  = wg * JPW;
  const bool rev = (dir == 1);

  // W_hh B-fragments: all 3 gates, my K-half. 24 frags = 96 VGPRs.
  short8 wh[3][8];
  {
    const float* pwd = whh + (size_t)dir * G3 * HID;
#pragma unroll
    for (int g = 0; g < 3; g++) {
      const float* pw = pwd + (size_t)(g * HID + j0 + l15) * HID + quad * 8;
#pragma unroll
      for (int c = 0; c < 8; c++) wh[g][c] = pack8(pw + (kh * 8 + c) * 32);
    }
  }
  // gate-thread constants/state: thread owns (batch b=tid>>3, hidden j0+2*jj, j0+2*jj+1)
  const float bhn0 = bhh[dir * G3 + 2 * HID + j0 + 2 * (tid & 7)];
  const float bhn1 = bhh[dir * G3 + 2 * HID + j0 + 2 * (tid & 7) + 1];
  float hr0 = 0.f, hr1 = 0.f;        // persistent h state (2 elems/thread)

  int* fl  = flags  + dir * NW * FSTR;
  int* cfl = cflags + dir * NW * FSTR;
  char* hb = (char*)(hbuf + (size_t)dir * 2 * 2048);   // [2 par][32KB]

  for (int s = 0; s < SEQ; s++) {
    const int t  = rev ? (SEQ - 1 - s) : s;
    const int c  = s >> 4;
    const int sl = s & 15;

    // Xi: wave w>=1 carries gate (w-1), both mi halves (mi stride = 512B).
    const int xig = (wave >= 1) ? (wave - 1) : 0;
    const char* xp = (const char*)Xic
        + (((((size_t)(c & 1)) * CH + sl) * NG + (dir * 96 + xig * 32 + wg)) * 128 + lane) * 8;
    ull xi0 = 0, xi1 = 0;
    if (wave >= 1 && sl != 0)   // chunk validated at its sl==0 step: pre-spin load OK
      asm volatile(
          "global_load_dwordx2 %0, %2, off sc0 sc1\n\t"
          "global_load_dwordx2 %1, %2, off offset:512 sc0 sc1\n\t"
          "s_waitcnt vmcnt(0)"
          : "=&v"(xi0), "=&v"(xi1) : "v"(xp) : "memory");

    if (wave == 0) {
      int it = 0;
      while (true) {
        int v = (s > 0 && lane < NW)
                  ? __hip_atomic_load(&fl[lane * FSTR], __ATOMIC_RELAXED, __HIP_MEMORY_SCOPE_AGENT)
                  : s;
        bool ok = __all(v >= s);
        if (ok && sl == 0) {
          int cnt = __hip_atomic_load(&prodcnt[c * CSTR], __ATOMIC_RELAXED, __HIP_MEMORY_SCOPE_AGENT);
          ok = (cnt >= NPROD);
        }
        if (ok) break;
        if (++it > SPIN_MAX) break;                    // bail (diagnostic insurance)
        __builtin_amdgcn_s_sleep(1);
      }
    }
    __syncthreads();
    if (wave >= 1 && sl == 0)   // slot only valid after prodcnt gate
      asm volatile(
          "global_load_dwordx2 %0, %2, off sc0 sc1\n\t"
          "global_load_dwordx2 %1, %2, off offset:512 sc0 sc1\n\t"
          "s_waitcnt vmcnt(0)"
          : "=&v"(xi0), "=&v"(xi1) : "v"(xp) : "memory");

    // ---- h projection partials: my (mi, K-half) slice, all 3 gates ----
    f32x4 p0 = (f32x4){0.f, 0.f, 0.f, 0.f};
    f32x4 p1 = (f32x4){0.f, 0.f, 0.f, 0.f};
    f32x4 p2 = (f32x4){0.f, 0.f, 0.f, 0.f};
    if (s > 0) {
      const char* hp = hb + (size_t)((s - 1) & 1) * 32768 + (size_t)mi * 16384
                     + (size_t)kh * 8192 + (size_t)lane * 16;
      short8 a0, a1, a2, a3, a4, a5, a6, a7;
      asm volatile(
          "global_load_dwordx4 %0, %8, off sc0 sc1\n\t"
          "global_load_dwordx4 %1, %8, off offset:1024 sc0 sc1\n\t"
          "global_load_dwordx4 %2, %8, off offset:2048 sc0 sc1\n\t"
          "global_load_dwordx4 %3, %8, off offset:3072 sc0 sc1\n\t"
          "global_load_dwordx4 %4, %9, off sc0 sc1\n\t"
          "global_load_dwordx4 %5, %9, off offset:1024 sc0 sc1\n\t"
          "global_load_dwordx4 %6, %9, off offset:2048 sc0 sc1\n\t"
          "global_load_dwordx4 %7, %9, off offset:3072 sc0 sc1\n\t"
          "s_waitcnt vmcnt(0)"
          : "=&v"(a0), "=&v"(a1), "=&v"(a2), "=&v"(a3),
            "=&v"(a4), "=&v"(a5), "=&v"(a6), "=&v"(a7)
          : "v"(hp), "v"(hp + 4096) : "memory");
      p0 = mfma16(a0, wh[0][0], p0); p1 = mfma16(a0, wh[1][0], p1); p2 = mfma16(a0, wh[2][0], p2);
      p0 = mfma16(a1, wh[0][1], p0); p1 = mfma16(a1, wh[1][1], p1); p2 = mfma16(a1, wh[2][1], p2);
      p0 = mfma16(a2, wh[0][2], p0); p1 = mfma16(a2, wh[1][2], p1); p2 = mfma16(a2, wh[2][2], p2);
      p0 = mfma16(a3, wh[0][3], p0); p1 = mfma16(a3, wh[1][3], p1); p2 = mfma16(a3, wh[2][3], p2);
      p0 = mfma16(a4, wh[0][4], p0); p1 = mfma16(a4, wh[1][4], p1); p2 = mfma16(a4, wh[2][4], p2);
      p0 = mfma16(a5, wh[0][5], p0); p1 = mfma16(a5, wh[1][5], p1); p2 = mfma16(a5, wh[2][5], p2);
      p0 = mfma16(a6, wh[0][6], p0); p1 = mfma16(a6, wh[1][6], p1); p2 = mfma16(a6, wh[2][6], p2);
      p0 = mfma16(a7, wh[0][7], p0); p1 = mfma16(a7, wh[1][7], p1); p2 = mfma16(a7, wh[2][7], p2);
    }

    // partial dump + Xi dump (conflict-free b128 / b64)
    {
      const int idx0 = mi * 64 + quad * 16 + l15;
      pbuf[kh * 384 + idx0]       = p0;
      pbuf[kh * 384 + 128 + idx0] = p1;
      pbuf[kh * 384 + 256 + idx0] = p2;
      if (wave >= 1) {
        xbuf3[xig * 128 + lane]      = xi0;   // mi = 0
        xbuf3[xig * 128 + 64 + lane] = xi1;   // mi = 1
      }
    }
    __syncthreads();

    // ---- gates + state + direct publish: 256 threads, 2 elems each ----
    {
      const int b  = tid >> 3;         // batch row 0..31
      const int jj = tid & 7;          // hidden pair within WG's 16
      const int gmi = b >> 4, gq = (b >> 2) & 3, r = b & 3;
      float h2[2];
      float hprev[2] = {hr0, hr1};
      float bhn2[2]  = {bhn0, bhn1};
#pragma unroll
      for (int e = 0; e < 2; e++) {
        const int j  = 2 * jj + e;
        const int rb = gmi * 64 + gq * 16 + j;
        float s0 = pbuf[rb][r]       + pbuf[384 + rb][r];
        float s1 = pbuf[128 + rb][r] + pbuf[512 + rb][r];
        float s2 = pbuf[256 + rb][r] + pbuf[640 + rb][r];
        float xr_ = bf2f((unsigned short)(xbuf3[rb]       >> (16 * r)));
        float xz_ = bf2f((unsigned short)(xbuf3[128 + rb] >> (16 * r)));
        float xn_ = bf2f((unsigned short)(xbuf3[256 + rb] >> (16 * r)));
        float rr  = 1.f / (1.f + __expf(-(s0 + xr_)));
        float zz  = 1.f / (1.f + __expf(-(s1 + xz_)));
        float a2v = xn_ + rr * (s2 + bhn2[e]);
        float ex  = __expf(2.f * a2v);
        float nn  = 1.f - 2.f / (ex + 1.f);        // tanh(a2v)
        h2[e] = (1.f - zz) * nn + zz * hprev[e];
      }
      hr0 = h2[0]; hr1 = h2[1];
      unsigned int val = (unsigned int)f2bf(h2[0]) | ((unsigned int)f2bf(h2[1]) << 16);
      const int k   = j0 + 2 * jj;
      const int kc  = k >> 5;
      const int q   = (k >> 3) & 3;
      const int l16 = (b & 15) + (q << 4);
      const int mib = b >> 4;
      char* pdst = hb + (size_t)(s & 1) * 32768 + (size_t)mib * 16384
                 + (size_t)kc * 1024 + (size_t)l16 * 16 + (size_t)(k & 7) * 2;
      asm volatile("global_store_dword %0, %1, off sc0 sc1" :: "v"(pdst), "v"(val) : "memory");
      if (WRITE_Y) {
        size_t yb = (((size_t)(t * 2 + mib) * 32 + (dir << 4) + kc) * 64 + l16) * 16 + (size_t)(k & 7) * 2;
        *(unsigned int*)((char*)yout + yb) = val;
      }
      if (s == SEQ - 1) {
        hout[((size_t)dir * 32 + b) * HID + k]     = h2[0];
        hout[((size_t)dir * 32 + b) * HID + k + 1] = h2[1];
      }
    }
    asm volatile("s_waitcnt vmcnt(0)" ::: "memory");   // drain publish stores
    __syncthreads();
    if (tid == 0) {
      const int fv = s + 1;
      __hip_atomic_store(&fl[wg * FSTR], fv, __ATOMIC_RELAXED, __HIP_MEMORY_SCOPE_AGENT);
      if (sl == 15)   // chunk flag for producers
        __hip_atomic_store(&cfl[wg * FSTR], fv, __ATOMIC_RELAXED, __HIP_MEMORY_SCOPE_AGENT);
    }
  }
}

extern "C" void kernel_launch(void* const* d_in, const int* in_sizes, int n_in,
                              void* d_out, int out_size, void* d_ws, size_t ws_size,
                              hipStream_t stream)
{
  const float* x       = (const float*)d_in[0];
  const float* w_ih_l0 = (const float*)d_in[1];
  const float* w_hh_l0 = (const float*)d_in[2];
  const float* b_ih_l0 = (const float*)d_in[3];
  const float* b_hh_l0 = (const float*)d_in[4];
  const float* w_ih_lr = (const float*)d_in[5];
  const float* w_hh_lr = (const float*)d_in[6];
  const float* b_ih_lr = (const float*)d_in[7];
  const float* b_hh_lr = (const float*)d_in[8];
  float* out = (float*)d_out;

  char* ws = (char*)d_ws;
  size_t off = 0;
  auto alloc = [&](size_t bytes) {
    char* p = ws + off;
    off += (bytes + 255) & ~(size_t)255;
    return p;
  };
  short8* y0   = (short8*)alloc((size_t)SEQ * 2 * 32 * 64 * 16);   // 64 MB
  short8* y1   = (short8*)alloc((size_t)SEQ * 2 * 32 * 64 * 16);   // 64 MB
  short8* wb   = (short8*)alloc((size_t)NG * 32 * 64 * 16);        // 6 MB
  short8* hbuf = (short8*)alloc((size_t)2 * 2 * 2048 * 16);        // 128 KB
  int*    flags   = (int*)alloc((size_t)3 * 2 * NW * FSTR * 4);    // 192 KB
  int*    cflags  = (int*)alloc((size_t)3 * 2 * NW * FSTR * 4);    // 192 KB
  int*    prodcnt = (int*)alloc((size_t)3 * NCH * CSTR * 4);       // 48 KB
  us4*    Xic  = (us4*)alloc((size_t)2 * CH * NG * 2 * 64 * 8);    // 6 MB
  // total ~140.6 MiB < proven-safe 151 MB

  hipMemsetAsync(flags,   0, (size_t)3 * 2 * NW * FSTR * 4, stream);
  hipMemsetAsync(cflags,  0, (size_t)3 * 2 * NW * FSTR * 4, stream);
  hipMemsetAsync(prodcnt, 0, (size_t)3 * NCH * CSTR * 4, stream);

  // ---- layer 0 (K=256, fp32 x read directly by producers) ----
  {
    int nc = NG * 8 * 64;
    cvt_wb<<<(nc + 255) / 256, 256, 0, stream>>>(w_ih_l0, wb, 8, nc);
    gru_mega<8, true><<<256, THREADS, 0, stream>>>(
        x, y0, wb, w_hh_l0, b_ih_l0, b_hh_l0, Xic, hbuf,
        flags, cflags, prodcnt, out);
  }
  // ---- layer 1 ----
  {
    int nc = NG * 32 * 64;
    cvt_wb<<<(nc + 255) / 256, 256, 0, stream>>>(w_ih_lr, wb, 32, nc);
    gru_mega<32, true><<<256, THREADS, 0, stream>>>(
        y0, y1, wb, w_hh_lr, b_ih_lr, b_hh_lr, Xic, hbuf,
        flags + 2 * NW * FSTR, cflags + 2 * NW * FSTR,
        prodcnt + NCH * CSTR, out + 2 * BATCH * HID);
  }
  // ---- layer 2 ----
  {
    int nc = NG * 32 * 64;
    cvt_wb<<<(nc + 255) / 256, 256, 0, stream>>>(w_ih_lr + (size_t)2 * G3 * 1024, wb, 32, nc);
    gru_mega<32, false><<<256, THREADS, 0, stream>>>(
        y1, nullptr, wb, w_hh_lr + (size_t)2 * G3 * HID,
        b_ih_lr + 2 * G3, b_hh_lr + 2 * G3, Xic, hbuf,
        flags + 4 * NW * FSTR, cflags + 4 * NW * FSTR,
        prodcnt + 2 * NCH * CSTR, out + 4 * BATCH * HID);
  }
}

// Round 6
// 9803.001 us; speedup vs baseline: 1.2033x; 1.1228x over previous
//
#include <hip/hip_runtime.h>
#include <stdint.h>

#define SEQ   1024
#define BATCH 32
#define HID   512
#define G3    1536
#define NW    32          // rec workgroups per direction
#define JPW   16          // hidden units owned per rec WG
#define THREADS 384       // 6 waves (g 0..2) x (mi 0..1) -- proven R0 structure
#define FSTR  256         // flag spacing in ints (1KB)
#define CSTR  64          // prodcnt spacing in ints (256B)
#define CH    16          // steps per Xi chunk
#define NCH   64          // chunks per layer (CH*NCH == SEQ)
#define NG    192         // gate-row groups of 16 (= 3072/16), ng = dir*96+g*32+wg
#define NPROD 192         // producer WGs
#define SPIN_MAX 65536    // spin bail-out; legit waits <<100us (proven neutral R5)

typedef __attribute__((ext_vector_type(8))) short  short8;
typedef __attribute__((ext_vector_type(4))) float  f32x4;
typedef __attribute__((ext_vector_type(4))) unsigned short us4;
typedef unsigned long long ull;

__device__ __forceinline__ unsigned short f2bf(float f) {
  union { float f; unsigned int u; } v; v.f = f;
  unsigned int u = v.u;
  return (unsigned short)((u + 0x7FFFu + ((u >> 16) & 1u)) >> 16);
}
__device__ __forceinline__ float bf2f(unsigned short u) {
  union { unsigned int i; float f; } v; v.i = ((unsigned int)u) << 16; return v.f;
}
__device__ __forceinline__ short8 pack8(const float* __restrict__ p) {
  short8 o;
#pragma unroll
  for (int i = 0; i < 8; i++) o[i] = (short)f2bf(p[i]);
  return o;
}
__device__ __forceinline__ f32x4 mfma16(short8 a, short8 b, f32x4 c) {
  return __builtin_amdgcn_mfma_f32_16x16x32_bf16(a, b, c, 0, 0, 0);
}

// fp32 W [3072][K] -> bf16 B-fragment chunks [ng][kc][64 lane] x 16B
__global__ void cvt_wb(const float* __restrict__ w, short8* __restrict__ out, int kcx, int nc) {
  int c = blockIdx.x * blockDim.x + threadIdx.x;
  if (c >= nc) return;
  int lane = c & 63, r = c >> 6;     // r = ng*kcx + kc
  int kc = r % kcx, ng = r / kcx;
  int n   = ng * 16 + (lane & 15);
  int col = kc * 32 + (lane >> 4) * 8;
  int K = kcx * 32;
  out[c] = pack8(w + (size_t)n * K + col);
}

// One dispatch per layer, grid=256: blocks 0..63 = recurrence (dir=blk>>5,
// wg=blk&31); blocks 64..255 = 192 producers. Rec side is byte-identical to
// the proven 9947us baseline (6 waves, redundant h reads, spread flags,
// sc0+sc1 everywhere) except: Xi load hoisted before the flag spin on
// already-validated chunks (sl != 0), and SPIN_MAX spin insurance.
// PRODUCER REGROUP (this round's change): p = (ngg 0..23) x (tg 0..7), each
// producer computes 8 ngs x 2 steps {2tg, 2tg+1} per chunk (was 16 ngs x 1
// step). Unique wb per producer-chunk halves and the 4 passes over it are
// temporally close (L2-friendly) -> producer LLC read rate drops 2-4x,
// cutting the LLC queueing contention that inflates every recurrence RT.
template<int KCX, bool WRITE_Y>
__global__ __launch_bounds__(THREADS, 1) void gru_mega(
    const void* __restrict__ Ain,      // KCX==8: fp32 x [T][32][256]; else short8 [T][2][KCX][64]
    short8* __restrict__ yout,         // [T][2][32][64] chunks (or null)
    const short8* __restrict__ wb,     // [NG][KCX][64] B-fragments
    const float* __restrict__ whh,     // [2][G3][HID]
    const float* __restrict__ bih,     // [3072]
    const float* __restrict__ bhh,     // [3072]
    us4* __restrict__ Xic,             // [2 slot][CH][NG][2 mi][64]
    short8* __restrict__ hbuf,         // [2 dir][2 par][2 mi][16 kc][64] chunks
    int* __restrict__ flags,           // [2][NW][FSTR]
    int* __restrict__ prodcnt,         // [NCH][CSTR]
    float* __restrict__ hout)          // [2][BATCH][HID] slice of d_out
{
  __shared__ float gbuf[4 * 512];      // [4][32][16] preactivations
  __shared__ float hold[512];          // [32][16] fp32 state

  const int tid  = threadIdx.x;
  const int lane = tid & 63;
  const int wave = tid >> 6;
  const int quad = lane >> 4;
  const int l15  = lane & 15;

  if (blockIdx.x >= 64) {
    // ================= producer =================
    const int p    = blockIdx.x - 64;  // 0..191
    const int tg   = p & 7;            // step pair {2tg, 2tg+1} within chunk
    const int ngg  = p >> 3;           // 0..23 -> ng range [ngg*8, ngg*8+8)
    const int dirp = (ngg >= 12) ? 1 : 0;
    int* fl = flags + dirp * NW * FSTR;

    for (int c = 0; c < NCH; c++) {
      const int tgt = (c >= 2) ? CH * (c - 1) : 0;   // slot free when dirp rec flags >= tgt
      if (wave == 0) {
        int it = 0;
        while (true) {
          int v = (lane < NW)
                    ? __hip_atomic_load(&fl[lane * FSTR], __ATOMIC_RELAXED, __HIP_MEMORY_SCOPE_AGENT)
                    : tgt;
          if (__all(v >= tgt)) break;
          if (++it > SPIN_MAX) break;            // insurance against hangs
          __builtin_amdgcn_s_sleep(4);
        }
      }
      __syncthreads();
      for (int sl2 = 0; sl2 < 2; sl2++) {
        const int sl = tg * 2 + sl2;
        const int s  = c * CH + sl;
        const int t  = dirp ? (SEQ - 1 - s) : s;
        for (int mi = 0; mi < 2; mi++) {
          short8 a[KCX];
          if constexpr (KCX == 8) {
            const float* xr = (const float*)Ain + ((size_t)t * 32 + mi * 16 + l15) * 256 + quad * 8;
#pragma unroll
            for (int kc = 0; kc < KCX; kc++) a[kc] = pack8(xr + kc * 32);
          } else {
            const short8* ap = (const short8*)Ain + ((size_t)(t * 2 + mi) * KCX) * 64 + lane;
#pragma unroll
            for (int kc = 0; kc < KCX; kc++) a[kc] = ap[kc * 64];
          }
          for (int ng = ngg * 8 + wave; ng < ngg * 8 + 8; ng += 6) {
            const short8* bp = wb + (size_t)ng * KCX * 64 + lane;
            f32x4 ac0 = (f32x4){0.f, 0.f, 0.f, 0.f};
            f32x4 ac1 = (f32x4){0.f, 0.f, 0.f, 0.f};
#pragma unroll
            for (int kc = 0; kc < KCX; kc += 2) {
              ac0 = mfma16(a[kc],     bp[kc * 64],       ac0);
              ac1 = mfma16(a[kc + 1], bp[(kc + 1) * 64], ac1);
            }
            const int n  = ng * 16 + l15;
            const int gg = (ng % 96) >> 5;                    // 0=r,1=z,2=n
            const float bias = bih[n] + (gg < 2 ? bhh[n] : 0.f);
            us4 o;
#pragma unroll
            for (int r = 0; r < 4; r++) o[r] = f2bf(ac0[r] + ac1[r] + bias);
            us4* dst = Xic + ((((size_t)(c & 1)) * CH + sl) * NG + ng) * 128 + mi * 64 + lane;
            asm volatile("global_store_dwordx2 %0, %1, off sc0 sc1" :: "v"(dst), "v"(o) : "memory");
          }
        }
      }
      asm volatile("s_waitcnt vmcnt(0)" ::: "memory");
      __syncthreads();
      if (tid == 0)
        __hip_atomic_fetch_add(&prodcnt[c * CSTR], 1, __ATOMIC_RELAXED, __HIP_MEMORY_SCOPE_AGENT);
    }
    return;
  }

  // ================= recurrence (R0 baseline structure) =================
  const int mi  = wave & 1;
  const int g   = wave >> 1;
  const int dir = blockIdx.x >> 5;
  const int wg  = blockIdx.x & 31;
  const int j0  = wg * JPW;
  const bool rev = (dir == 1);
  const int ngR = dir * 96 + g * 32 + wg;

  short8 wh[16];
  {
    const float* pw = whh + (size_t)dir * G3 * HID + (size_t)(g * HID + j0 + l15) * HID + quad * 8;
#pragma unroll
    for (int kc = 0; kc < 16; kc++) wh[kc] = pack8(pw + kc * 32);
  }
  const float bh = bhh[dir * G3 + g * HID + j0 + l15];

  for (int idx = tid; idx < 512; idx += THREADS) hold[idx] = 0.f;
  __syncthreads();

  int* fl = flags + dir * NW * FSTR;
  char* hb = (char*)(hbuf + (size_t)dir * 2 * 2048);   // [2 par][32KB]

  for (int s = 0; s < SEQ; s++) {
    const int t  = rev ? (SEQ - 1 - s) : s;
    const int c  = s >> 4;
    const int sl = s & 15;

    const char* xp = (const char*)Xic
        + (((((size_t)(c & 1)) * CH + sl) * NG + ngR) * 128 + mi * 64 + lane) * 8;
    ull xi64 = 0;
    if (sl != 0)   // chunk validated at its sl==0 step: pre-spin load overlaps the wait
      asm volatile("global_load_dwordx2 %0, %1, off sc0 sc1\n\ts_waitcnt vmcnt(0)"
                   : "=v"(xi64) : "v"(xp) : "memory");

    if (wave == 0) {
      int it = 0;
      while (true) {
        int v = (s > 0 && lane < NW)
                  ? __hip_atomic_load(&fl[lane * FSTR], __ATOMIC_RELAXED, __HIP_MEMORY_SCOPE_AGENT)
                  : s;
        bool ok = __all(v >= s);
        if (ok && sl == 0) {
          int cnt = __hip_atomic_load(&prodcnt[c * CSTR], __ATOMIC_RELAXED, __HIP_MEMORY_SCOPE_AGENT);
          ok = (cnt >= NPROD);
        }
        if (ok) break;
        if (++it > SPIN_MAX) break;                    // insurance against hangs
        __builtin_amdgcn_s_sleep(1);
      }
    }
    __syncthreads();
    if (sl == 0)   // slot only valid after the prodcnt gate
      asm volatile("global_load_dwordx2 %0, %1, off sc0 sc1\n\ts_waitcnt vmcnt(0)"
                   : "=v"(xi64) : "v"(xp) : "memory");

    f32x4 p0 = (f32x4){0.f, 0.f, 0.f, 0.f};
    f32x4 p1 = (f32x4){0.f, 0.f, 0.f, 0.f};

    if (s > 0) {
      const char* hp = hb + (size_t)((s - 1) & 1) * 32768 + (size_t)mi * 16384 + (size_t)lane * 16;
      short8 a0, a1, a2, a3, a4, a5, a6, a7, a8, a9, a10, a11, a12, a13, a14, a15;
      asm volatile(
          "global_load_dwordx4 %0, %16, off sc0 sc1\n\t"
          "global_load_dwordx4 %1, %16, off offset:1024 sc0 sc1\n\t"
          "global_load_dwordx4 %2, %16, off offset:2048 sc0 sc1\n\t"
          "global_load_dwordx4 %3, %16, off offset:3072 sc0 sc1\n\t"
          "global_load_dwordx4 %4, %17, off sc0 sc1\n\t"
          "global_load_dwordx4 %5, %17, off offset:1024 sc0 sc1\n\t"
          "global_load_dwordx4 %6, %17, off offset:2048 sc0 sc1\n\t"
          "global_load_dwordx4 %7, %17, off offset:3072 sc0 sc1\n\t"
          "global_load_dwordx4 %8, %18, off sc0 sc1\n\t"
          "global_load_dwordx4 %9, %18, off offset:1024 sc0 sc1\n\t"
          "global_load_dwordx4 %10, %18, off offset:2048 sc0 sc1\n\t"
          "global_load_dwordx4 %11, %18, off offset:3072 sc0 sc1\n\t"
          "global_load_dwordx4 %12, %19, off sc0 sc1\n\t"
          "global_load_dwordx4 %13, %19, off offset:1024 sc0 sc1\n\t"
          "global_load_dwordx4 %14, %19, off offset:2048 sc0 sc1\n\t"
          "global_load_dwordx4 %15, %19, off offset:3072 sc0 sc1\n\t"
          "s_waitcnt vmcnt(0)"
          : "=&v"(a0), "=&v"(a1), "=&v"(a2), "=&v"(a3),
            "=&v"(a4), "=&v"(a5), "=&v"(a6), "=&v"(a7),
            "=&v"(a8), "=&v"(a9), "=&v"(a10), "=&v"(a11),
            "=&v"(a12), "=&v"(a13), "=&v"(a14), "=&v"(a15)
          : "v"(hp), "v"(hp + 4096), "v"(hp + 8192), "v"(hp + 12288)
          : "memory");
      p0 = mfma16(a0,  wh[0],  p0);
      p1 = mfma16(a1,  wh[1],  p1);
      p0 = mfma16(a2,  wh[2],  p0);
      p1 = mfma16(a3,  wh[3],  p1);
      p0 = mfma16(a4,  wh[4],  p0);
      p1 = mfma16(a5,  wh[5],  p1);
      p0 = mfma16(a6,  wh[6],  p0);
      p1 = mfma16(a7,  wh[7],  p1);
      p0 = mfma16(a8,  wh[8],  p0);
      p1 = mfma16(a9,  wh[9],  p1);
      p0 = mfma16(a10, wh[10], p0);
      p1 = mfma16(a11, wh[11], p1);
      p0 = mfma16(a12, wh[12], p0);
      p1 = mfma16(a13, wh[13], p1);
      p0 = mfma16(a14, wh[14], p0);
      p1 = mfma16(a15, wh[15], p1);
    }

    // ---- merge Xi + h-projection; dump preactivations (D: m = mi*16+quad*4+r) ----
#pragma unroll
    for (int r = 0; r < 4; r++) {
      int m = mi * 16 + quad * 4 + r;
      float xv = bf2f((unsigned short)(xi64 >> (16 * r)));
      if (g < 2) {
        gbuf[(g * 32 + m) * JPW + l15] = xv + p0[r] + p1[r];
      } else {
        gbuf[(2 * 32 + m) * JPW + l15] = xv;
        gbuf[(3 * 32 + m) * JPW + l15] = bh + p0[r] + p1[r];
      }
    }
    __syncthreads();

    // ---- gates + state + direct publish: threads 0..255, 2 elems each ----
    if (tid < 256) {
      int b = tid >> 3, jj = tid & 7;
      int e0 = b * 16 + 2 * jj;
      float h2[2];
#pragma unroll
      for (int e = 0; e < 2; e++) {
        int idx = e0 + e;
        int j = (idx & 15);
        float pr = gbuf[(0 * 32 + b) * JPW + j];
        float pz = gbuf[(1 * 32 + b) * JPW + j];
        float px = gbuf[(2 * 32 + b) * JPW + j];
        float ph = gbuf[(3 * 32 + b) * JPW + j];
        float rr = 1.f / (1.f + __expf(-pr));
        float zz = 1.f / (1.f + __expf(-pz));
        float a2 = px + rr * ph;
        float ex = __expf(2.f * a2);
        float nn = 1.f - 2.f / (ex + 1.f);        // tanh(a2)
        float hp2 = hold[idx];
        float hnew = (1.f - zz) * nn + zz * hp2;
        hold[idx] = hnew;
        h2[e] = hnew;
      }
      unsigned int val = (unsigned int)f2bf(h2[0]) | ((unsigned int)f2bf(h2[1]) << 16);
      int k  = j0 + 2 * jj;
      int kc = k >> 5;
      int q  = (k >> 3) & 3;
      int l16 = (b & 15) + (q << 4);
      int mib = b >> 4;
      char* dst = hb + (size_t)(s & 1) * 32768 + (size_t)mib * 16384
                + (size_t)kc * 1024 + (size_t)l16 * 16 + (size_t)(k & 7) * 2;
      asm volatile("global_store_dword %0, %1, off sc0 sc1" :: "v"(dst), "v"(val) : "memory");
      if (WRITE_Y) {
        size_t yb = (((size_t)(t * 2 + mib) * 32 + (dir << 4) + kc) * 64 + l16) * 16 + (size_t)(k & 7) * 2;
        *(unsigned int*)((char*)yout + yb) = val;
      }
      if (s == SEQ - 1) {
        hout[((size_t)dir * 32 + b) * HID + k]     = h2[0];
        hout[((size_t)dir * 32 + b) * HID + k + 1] = h2[1];
      }
    }
    asm volatile("s_waitcnt vmcnt(0)" ::: "memory");   // drain sc1 publish stores
    __syncthreads();
    if (tid == 0)
      __hip_atomic_store(&fl[wg * FSTR], s + 1, __ATOMIC_RELAXED, __HIP_MEMORY_SCOPE_AGENT);
  }
}

extern "C" void kernel_launch(void* const* d_in, const int* in_sizes, int n_in,
                              void* d_out, int out_size, void* d_ws, size_t ws_size,
                              hipStream_t stream)
{
  const float* x       = (const float*)d_in[0];
  const float* w_ih_l0 = (const float*)d_in[1];
  const float* w_hh_l0 = (const float*)d_in[2];
  const float* b_ih_l0 = (const float*)d_in[3];
  const float* b_hh_l0 = (const float*)d_in[4];
  const float* w_ih_lr = (const float*)d_in[5];
  const float* w_hh_lr = (const float*)d_in[6];
  const float* b_ih_lr = (const float*)d_in[7];
  const float* b_hh_lr = (const float*)d_in[8];
  float* out = (float*)d_out;

  char* ws = (char*)d_ws;
  size_t off = 0;
  auto alloc = [&](size_t bytes) {
    char* p = ws + off;
    off += (bytes + 255) & ~(size_t)255;
    return p;
  };
  short8* y0   = (short8*)alloc((size_t)SEQ * 2 * 32 * 64 * 16);   // 64 MB
  short8* y1   = (short8*)alloc((size_t)SEQ * 2 * 32 * 64 * 16);   // 64 MB
  short8* wb   = (short8*)alloc((size_t)NG * 32 * 64 * 16);        // 6 MB
  short8* hbuf = (short8*)alloc((size_t)2 * 2 * 2048 * 16);        // 128 KB
  int*    flags   = (int*)alloc((size_t)3 * 2 * NW * FSTR * 4);    // 192 KB
  int*    prodcnt = (int*)alloc((size_t)3 * NCH * CSTR * 4);       // 48 KB
  us4*    Xic  = (us4*)alloc((size_t)2 * CH * NG * 2 * 64 * 8);    // 6 MB
  // total ~140.4 MiB < proven-safe 151 MB

  hipMemsetAsync(flags, 0, (size_t)3 * 2 * NW * FSTR * 4, stream);
  hipMemsetAsync(prodcnt, 0, (size_t)3 * NCH * CSTR * 4, stream);

  // ---- layer 0 (K=256, fp32 x read directly by producers) ----
  {
    int nc = NG * 8 * 64;
    cvt_wb<<<(nc + 255) / 256, 256, 0, stream>>>(w_ih_l0, wb, 8, nc);
    gru_mega<8, true><<<256, THREADS, 0, stream>>>(
        x, y0, wb, w_hh_l0, b_ih_l0, b_hh_l0, Xic, hbuf, flags, prodcnt, out);
  }
  // ---- layer 1 ----
  {
    int nc = NG * 32 * 64;
    cvt_wb<<<(nc + 255) / 256, 256, 0, stream>>>(w_ih_lr, wb, 32, nc);
    gru_mega<32, true><<<256, THREADS, 0, stream>>>(
        y0, y1, wb, w_hh_lr, b_ih_lr, b_hh_lr, Xic, hbuf,
        flags + 2 * NW * FSTR, prodcnt + NCH * CSTR, out + 2 * BATCH * HID);
  }
  // ---- layer 2 ----
  {
    int nc = NG * 32 * 64;
    cvt_wb<<<(nc + 255) / 256, 256, 0, stream>>>(w_ih_lr + (size_t)2 * G3 * 1024, wb, 32, nc);
    gru_mega<32, false><<<256, THREADS, 0, stream>>>(
        y1, nullptr, wb, w_hh_lr + (size_t)2 * G3 * HID,
        b_ih_lr + 2 * G3, b_hh_lr + 2 * G3, Xic, hbuf,
        flags + 4 * NW * FSTR, prodcnt + 2 * NCH * CSTR, out + 4 * BATCH * HID);
  }
}

// Round 7
// 9497.805 us; speedup vs baseline: 1.2420x; 1.0321x over previous
//
#include <hip/hip_runtime.h>
#include <stdint.h>

#define SEQ   1024
#define BATCH 32
#define HID   512
#define G3    1536
#define NW    32          // rec workgroups per direction
#define JPW   16          // hidden units owned per rec WG
#define THREADS 384       // 6 waves (g 0..2) x (mi 0..1) -- proven R0 structure
#define FSTR  256         // flag spacing in ints (1KB)
#define CSTR  64          // prodcnt spacing in ints (256B)
#define CH    16          // steps per Xi chunk
#define NCH   64          // chunks per layer (CH*NCH == SEQ)
#define NG    192         // gate-row groups of 16 (= 3072/16), ng = dir*96+g*32+wg
#define NPROD 192         // producer WGs
#define SPIN_MAX 65536    // spin bail-out; legit waits <<100us (proven neutral R5/R6)

typedef __attribute__((ext_vector_type(8))) short  short8;
typedef __attribute__((ext_vector_type(4))) float  f32x4;
typedef __attribute__((ext_vector_type(4))) unsigned short us4;
typedef unsigned long long ull;

__device__ __forceinline__ unsigned short f2bf(float f) {
  union { float f; unsigned int u; } v; v.f = f;
  unsigned int u = v.u;
  return (unsigned short)((u + 0x7FFFu + ((u >> 16) & 1u)) >> 16);
}
__device__ __forceinline__ float bf2f(unsigned short u) {
  union { unsigned int i; float f; } v; v.i = ((unsigned int)u) << 16; return v.f;
}
__device__ __forceinline__ short8 pack8(const float* __restrict__ p) {
  short8 o;
#pragma unroll
  for (int i = 0; i < 8; i++) o[i] = (short)f2bf(p[i]);
  return o;
}
__device__ __forceinline__ f32x4 mfma16(short8 a, short8 b, f32x4 c) {
  return __builtin_amdgcn_mfma_f32_16x16x32_bf16(a, b, c, 0, 0, 0);
}

// fp32 W [3072][K] -> bf16 B-fragment chunks [ng][kc][64 lane] x 16B
__global__ void cvt_wb(const float* __restrict__ w, short8* __restrict__ out, int kcx, int nc) {
  int c = blockIdx.x * blockDim.x + threadIdx.x;
  if (c >= nc) return;
  int lane = c & 63, r = c >> 6;     // r = ng*kcx + kc
  int kc = r % kcx, ng = r / kcx;
  int n   = ng * 16 + (lane & 15);
  int col = kc * 32 + (lane >> 4) * 8;
  int K = kcx * 32;
  out[c] = pack8(w + (size_t)n * K + col);
}

// One dispatch per layer, grid=256: blocks 0..63 = recurrence (dir=blk>>5,
// wg=blk&31); blocks 64..255 = 192 producers (R0 grouping: 16 ngs x 1 step --
// R6's 8x2 regroup raised FETCH 63% for no gain, reverted).
// THIS ROUND: coalesced publish. The 1KB of h a WG publishes per step is two
// contiguous 512B regions (hb + par*32K + mi*16K + wg*512) in the existing
// granule layout; same for yout. Gate threads stage their packed dwords into
// a 1KB LDS buffer laid out exactly like the global layout; wave 0 alone then
// re-reads it as 64 x b128 and issues 64 lane-contiguous dwordx4 stores
// (8 LLC lines) for h + 64 for y, drains vmcnt, sets the flag. Replaces the
// 256+256 scattered 4B write-through transactions whose serialized acks were
// the prime suspect for the unexplained ~4500cy/step. Consumer layout is
// byte-identical to the proven baseline. Also removes one __syncthreads from
// the chain (publish+flag live entirely in wave 0; the next step's post-spin
// barrier resynchronizes).
template<int KCX, bool WRITE_Y>
__global__ __launch_bounds__(THREADS, 1) void gru_mega(
    const void* __restrict__ Ain,      // KCX==8: fp32 x [T][32][256]; else short8 [T][2][KCX][64]
    short8* __restrict__ yout,         // [T][2][32][64] chunks (or null)
    const short8* __restrict__ wb,     // [NG][KCX][64] B-fragments
    const float* __restrict__ whh,     // [2][G3][HID]
    const float* __restrict__ bih,     // [3072]
    const float* __restrict__ bhh,     // [3072]
    us4* __restrict__ Xic,             // [2 slot][CH][NG][2 mi][64]
    short8* __restrict__ hbuf,         // [2 dir][2 par][2 mi][16 kc][64] chunks
    int* __restrict__ flags,           // [2][NW][FSTR]
    int* __restrict__ prodcnt,         // [NCH][CSTR]
    float* __restrict__ hout)          // [2][BATCH][HID] slice of d_out
{
  __shared__ float gbuf[4 * 512];        // [4][32][16] preactivations
  __shared__ float hold[512];            // [32][16] fp32 state
  __shared__ unsigned int sbuf[256];     // 1KB publish staging, global-layout order

  const int tid  = threadIdx.x;
  const int lane = tid & 63;
  const int wave = tid >> 6;
  const int quad = lane >> 4;
  const int l15  = lane & 15;

  if (blockIdx.x >= 64) {
    // ================= producer (R0 grouping) =================
    const int p    = blockIdx.x - 64;  // 0..191
    const int tg   = p & 15;           // sl within chunk (CH==16)
    const int ngg  = p >> 4;           // 0..11 -> ng range [ngg*16, ngg*16+16)
    const int dirp = (ngg >= 6) ? 1 : 0;
    int* fl = flags + dirp * NW * FSTR;

    for (int c = 0; c < NCH; c++) {
      const int tgt = (c >= 2) ? CH * (c - 1) : 0;   // slot free when dirp rec flags >= tgt
      if (wave == 0) {
        int it = 0;
        while (true) {
          int v = (lane < NW)
                    ? __hip_atomic_load(&fl[lane * FSTR], __ATOMIC_RELAXED, __HIP_MEMORY_SCOPE_AGENT)
                    : tgt;
          if (__all(v >= tgt)) break;
          if (++it > SPIN_MAX) break;            // insurance against hangs
          __builtin_amdgcn_s_sleep(4);
        }
      }
      __syncthreads();
      const int sl = tg;
      const int s  = c * CH + sl;
      const int t  = dirp ? (SEQ - 1 - s) : s;
      for (int mi = 0; mi < 2; mi++) {
        short8 a[KCX];
        if constexpr (KCX == 8) {
          const float* xr = (const float*)Ain + ((size_t)t * 32 + mi * 16 + l15) * 256 + quad * 8;
#pragma unroll
          for (int kc = 0; kc < KCX; kc++) a[kc] = pack8(xr + kc * 32);
        } else {
          const short8* ap = (const short8*)Ain + ((size_t)(t * 2 + mi) * KCX) * 64 + lane;
#pragma unroll
          for (int kc = 0; kc < KCX; kc++) a[kc] = ap[kc * 64];
        }
        for (int ng = ngg * 16 + wave; ng < ngg * 16 + 16; ng += 6) {
          const short8* bp = wb + (size_t)ng * KCX * 64 + lane;
          f32x4 ac0 = (f32x4){0.f, 0.f, 0.f, 0.f};
          f32x4 ac1 = (f32x4){0.f, 0.f, 0.f, 0.f};
#pragma unroll
          for (int kc = 0; kc < KCX; kc += 2) {
            ac0 = mfma16(a[kc],     bp[kc * 64],       ac0);
            ac1 = mfma16(a[kc + 1], bp[(kc + 1) * 64], ac1);
          }
          const int n  = ng * 16 + l15;
          const int gg = (ng % 96) >> 5;                    // 0=r,1=z,2=n
          const float bias = bih[n] + (gg < 2 ? bhh[n] : 0.f);
          us4 o;
#pragma unroll
          for (int r = 0; r < 4; r++) o[r] = f2bf(ac0[r] + ac1[r] + bias);
          us4* dst = Xic + ((((size_t)(c & 1)) * CH + sl) * NG + ng) * 128 + mi * 64 + lane;
          asm volatile("global_store_dwordx2 %0, %1, off sc0 sc1" :: "v"(dst), "v"(o) : "memory");
        }
      }
      asm volatile("s_waitcnt vmcnt(0)" ::: "memory");
      __syncthreads();
      if (tid == 0)
        __hip_atomic_fetch_add(&prodcnt[c * CSTR], 1, __ATOMIC_RELAXED, __HIP_MEMORY_SCOPE_AGENT);
    }
    return;
  }

  // ================= recurrence (R0 structure, coalesced publish) ============
  const int mi  = wave & 1;
  const int g   = wave >> 1;
  const int dir = blockIdx.x >> 5;
  const int wg  = blockIdx.x & 31;
  const int j0  = wg * JPW;
  const bool rev = (dir == 1);
  const int ngR = dir * 96 + g * 32 + wg;

  short8 wh[16];
  {
    const float* pw = whh + (size_t)dir * G3 * HID + (size_t)(g * HID + j0 + l15) * HID + quad * 8;
#pragma unroll
    for (int kc = 0; kc < 16; kc++) wh[kc] = pack8(pw + kc * 32);
  }
  const float bh = bhh[dir * G3 + g * HID + j0 + l15];

  for (int idx = tid; idx < 512; idx += THREADS) hold[idx] = 0.f;
  __syncthreads();

  int* fl = flags + dir * NW * FSTR;
  char* hb = (char*)(hbuf + (size_t)dir * 2 * 2048);   // [2 par][32KB]

  for (int s = 0; s < SEQ; s++) {
    const int t  = rev ? (SEQ - 1 - s) : s;
    const int c  = s >> 4;
    const int sl = s & 15;

    const char* xp = (const char*)Xic
        + (((((size_t)(c & 1)) * CH + sl) * NG + ngR) * 128 + mi * 64 + lane) * 8;
    ull xi64 = 0;
    if (sl != 0)   // chunk validated at its sl==0 step: pre-spin load overlaps the wait
      asm volatile("global_load_dwordx2 %0, %1, off sc0 sc1\n\ts_waitcnt vmcnt(0)"
                   : "=v"(xi64) : "v"(xp) : "memory");

    if (wave == 0) {
      int it = 0;
      while (true) {
        int v = (s > 0 && lane < NW)
                  ? __hip_atomic_load(&fl[lane * FSTR], __ATOMIC_RELAXED, __HIP_MEMORY_SCOPE_AGENT)
                  : s;
        bool ok = __all(v >= s);
        if (ok && sl == 0) {
          int cnt = __hip_atomic_load(&prodcnt[c * CSTR], __ATOMIC_RELAXED, __HIP_MEMORY_SCOPE_AGENT);
          ok = (cnt >= NPROD);
        }
        if (ok) break;
        if (++it > SPIN_MAX) break;                    // insurance against hangs
        __builtin_amdgcn_s_sleep(1);
      }
    }
    __syncthreads();
    if (sl == 0)   // slot only valid after the prodcnt gate
      asm volatile("global_load_dwordx2 %0, %1, off sc0 sc1\n\ts_waitcnt vmcnt(0)"
                   : "=v"(xi64) : "v"(xp) : "memory");

    f32x4 p0 = (f32x4){0.f, 0.f, 0.f, 0.f};
    f32x4 p1 = (f32x4){0.f, 0.f, 0.f, 0.f};

    if (s > 0) {
      const char* hp = hb + (size_t)((s - 1) & 1) * 32768 + (size_t)mi * 16384 + (size_t)lane * 16;
      short8 a0, a1, a2, a3, a4, a5, a6, a7, a8, a9, a10, a11, a12, a13, a14, a15;
      asm volatile(
          "global_load_dwordx4 %0, %16, off sc0 sc1\n\t"
          "global_load_dwordx4 %1, %16, off offset:1024 sc0 sc1\n\t"
          "global_load_dwordx4 %2, %16, off offset:2048 sc0 sc1\n\t"
          "global_load_dwordx4 %3, %16, off offset:3072 sc0 sc1\n\t"
          "global_load_dwordx4 %4, %17, off sc0 sc1\n\t"
          "global_load_dwordx4 %5, %17, off offset:1024 sc0 sc1\n\t"
          "global_load_dwordx4 %6, %17, off offset:2048 sc0 sc1\n\t"
          "global_load_dwordx4 %7, %17, off offset:3072 sc0 sc1\n\t"
          "global_load_dwordx4 %8, %18, off sc0 sc1\n\t"
          "global_load_dwordx4 %9, %18, off offset:1024 sc0 sc1\n\t"
          "global_load_dwordx4 %10, %18, off offset:2048 sc0 sc1\n\t"
          "global_load_dwordx4 %11, %18, off offset:3072 sc0 sc1\n\t"
          "global_load_dwordx4 %12, %19, off sc0 sc1\n\t"
          "global_load_dwordx4 %13, %19, off offset:1024 sc0 sc1\n\t"
          "global_load_dwordx4 %14, %19, off offset:2048 sc0 sc1\n\t"
          "global_load_dwordx4 %15, %19, off offset:3072 sc0 sc1\n\t"
          "s_waitcnt vmcnt(0)"
          : "=&v"(a0), "=&v"(a1), "=&v"(a2), "=&v"(a3),
            "=&v"(a4), "=&v"(a5), "=&v"(a6), "=&v"(a7),
            "=&v"(a8), "=&v"(a9), "=&v"(a10), "=&v"(a11),
            "=&v"(a12), "=&v"(a13), "=&v"(a14), "=&v"(a15)
          : "v"(hp), "v"(hp + 4096), "v"(hp + 8192), "v"(hp + 12288)
          : "memory");
      p0 = mfma16(a0,  wh[0],  p0);
      p1 = mfma16(a1,  wh[1],  p1);
      p0 = mfma16(a2,  wh[2],  p0);
      p1 = mfma16(a3,  wh[3],  p1);
      p0 = mfma16(a4,  wh[4],  p0);
      p1 = mfma16(a5,  wh[5],  p1);
      p0 = mfma16(a6,  wh[6],  p0);
      p1 = mfma16(a7,  wh[7],  p1);
      p0 = mfma16(a8,  wh[8],  p0);
      p1 = mfma16(a9,  wh[9],  p1);
      p0 = mfma16(a10, wh[10], p0);
      p1 = mfma16(a11, wh[11], p1);
      p0 = mfma16(a12, wh[12], p0);
      p1 = mfma16(a13, wh[13], p1);
      p0 = mfma16(a14, wh[14], p0);
      p1 = mfma16(a15, wh[15], p1);
    }

    // ---- merge Xi + h-projection; dump preactivations (D: m = mi*16+quad*4+r) ----
#pragma unroll
    for (int r = 0; r < 4; r++) {
      int m = mi * 16 + quad * 4 + r;
      float xv = bf2f((unsigned short)(xi64 >> (16 * r)));
      if (g < 2) {
        gbuf[(g * 32 + m) * JPW + l15] = xv + p0[r] + p1[r];
      } else {
        gbuf[(2 * 32 + m) * JPW + l15] = xv;
        gbuf[(3 * 32 + m) * JPW + l15] = bh + p0[r] + p1[r];
      }
    }
    __syncthreads();

    // ---- gates + state: threads 0..255, 2 elems each; stage publish in LDS ----
    if (tid < 256) {
      int b = tid >> 3, jj = tid & 7;
      int e0 = b * 16 + 2 * jj;
      float h2[2];
#pragma unroll
      for (int e = 0; e < 2; e++) {
        int idx = e0 + e;
        int j = (idx & 15);
        float pr = gbuf[(0 * 32 + b) * JPW + j];
        float pz = gbuf[(1 * 32 + b) * JPW + j];
        float px = gbuf[(2 * 32 + b) * JPW + j];
        float ph = gbuf[(3 * 32 + b) * JPW + j];
        float rr = 1.f / (1.f + __expf(-pr));
        float zz = 1.f / (1.f + __expf(-pz));
        float a2 = px + rr * ph;
        float ex = __expf(2.f * a2);
        float nn = 1.f - 2.f / (ex + 1.f);        // tanh(a2)
        float hp2 = hold[idx];
        float hnew = (1.f - zz) * nn + zz * hp2;
        hold[idx] = hnew;
        h2[e] = hnew;
      }
      unsigned int val = (unsigned int)f2bf(h2[0]) | ((unsigned int)f2bf(h2[1]) << 16);
      // stage in global-layout order: [mi=b>>4][granule gl=(b&15)+(jj>>2)*16][dword jj&3]
      sbuf[(b >> 4) * 128 + ((b & 15) + (jj >> 2) * 16) * 4 + (jj & 3)] = val;
      if (s == SEQ - 1) {
        int k = j0 + 2 * jj;
        hout[((size_t)dir * 32 + b) * HID + k]     = h2[0];
        hout[((size_t)dir * 32 + b) * HID + k + 1] = h2[1];
      }
    }
    __syncthreads();   // sbuf ready

    // ---- coalesced publish + flag: wave 0 only (others flow to next spin) ----
    if (wave == 0) {
      const int lm  = lane >> 5;          // mi half
      const int l31 = lane & 31;          // granule within the WG's 512B region
      f32x4 v = *(f32x4*)((char*)sbuf + (size_t)lane * 16);
      char* hdst = hb + (size_t)(s & 1) * 32768 + (size_t)lm * 16384
                 + (size_t)wg * 512 + (size_t)l31 * 16;
      asm volatile("global_store_dwordx4 %0, %1, off sc0 sc1" :: "v"(hdst), "v"(v) : "memory");
      if (WRITE_Y) {
        char* ydst = (char*)yout
            + (((size_t)(t * 2 + lm) * 32 + (dir << 4)) * 64) * 16
            + (size_t)wg * 512 + (size_t)l31 * 16;
        *(f32x4*)ydst = v;   // plain coalesced store (cached path)
      }
      asm volatile("s_waitcnt vmcnt(0)" ::: "memory");
      if (tid == 0)
        __hip_atomic_store(&fl[wg * FSTR], s + 1, __ATOMIC_RELAXED, __HIP_MEMORY_SCOPE_AGENT);
    }
    // no barrier here: the next iteration's post-spin __syncthreads resyncs,
    // and no thread touches gbuf/hold/sbuf before passing it.
  }
}

extern "C" void kernel_launch(void* const* d_in, const int* in_sizes, int n_in,
                              void* d_out, int out_size, void* d_ws, size_t ws_size,
                              hipStream_t stream)
{
  const float* x       = (const float*)d_in[0];
  const float* w_ih_l0 = (const float*)d_in[1];
  const float* w_hh_l0 = (const float*)d_in[2];
  const float* b_ih_l0 = (const float*)d_in[3];
  const float* b_hh_l0 = (const float*)d_in[4];
  const float* w_ih_lr = (const float*)d_in[5];
  const float* w_hh_lr = (const float*)d_in[6];
  const float* b_ih_lr = (const float*)d_in[7];
  const float* b_hh_lr = (const float*)d_in[8];
  float* out = (float*)d_out;

  char* ws = (char*)d_ws;
  size_t off = 0;
  auto alloc = [&](size_t bytes) {
    char* p = ws + off;
    off += (bytes + 255) & ~(size_t)255;
    return p;
  };
  short8* y0   = (short8*)alloc((size_t)SEQ * 2 * 32 * 64 * 16);   // 64 MB
  short8* y1   = (short8*)alloc((size_t)SEQ * 2 * 32 * 64 * 16);   // 64 MB
  short8* wb   = (short8*)alloc((size_t)NG * 32 * 64 * 16);        // 6 MB
  short8* hbuf = (short8*)alloc((size_t)2 * 2 * 2048 * 16);        // 128 KB
  int*    flags   = (int*)alloc((size_t)3 * 2 * NW * FSTR * 4);    // 192 KB
  int*    prodcnt = (int*)alloc((size_t)3 * NCH * CSTR * 4);       // 48 KB
  us4*    Xic  = (us4*)alloc((size_t)2 * CH * NG * 2 * 64 * 8);    // 6 MB
  // total ~140.4 MiB < proven-safe 151 MB

  hipMemsetAsync(flags, 0, (size_t)3 * 2 * NW * FSTR * 4, stream);
  hipMemsetAsync(prodcnt, 0, (size_t)3 * NCH * CSTR * 4, stream);

  // ---- layer 0 (K=256, fp32 x read directly by producers) ----
  {
    int nc = NG * 8 * 64;
    cvt_wb<<<(nc + 255) / 256, 256, 0, stream>>>(w_ih_l0, wb, 8, nc);
    gru_mega<8, true><<<256, THREADS, 0, stream>>>(
        x, y0, wb, w_hh_l0, b_ih_l0, b_hh_l0, Xic, hbuf, flags, prodcnt, out);
  }
  // ---- layer 1 ----
  {
    int nc = NG * 32 * 64;
    cvt_wb<<<(nc + 255) / 256, 256, 0, stream>>>(w_ih_lr, wb, 32, nc);
    gru_mega<32, true><<<256, THREADS, 0, stream>>>(
        y0, y1, wb, w_hh_lr, b_ih_lr, b_hh_lr, Xic, hbuf,
        flags + 2 * NW * FSTR, prodcnt + NCH * CSTR, out + 2 * BATCH * HID);
  }
  // ---- layer 2 ----
  {
    int nc = NG * 32 * 64;
    cvt_wb<<<(nc + 255) / 256, 256, 0, stream>>>(w_ih_lr + (size_t)2 * G3 * 1024, wb, 32, nc);
    gru_mega<32, false><<<256, THREADS, 0, stream>>>(
        y1, nullptr, wb, w_hh_lr + (size_t)2 * G3 * HID,
        b_ih_lr + 2 * G3, b_hh_lr + 2 * G3, Xic, hbuf,
        flags + 4 * NW * FSTR, prodcnt + 2 * NCH * CSTR, out + 4 * BATCH * HID);
  }
}

// Round 9
// 9451.499 us; speedup vs baseline: 1.2481x; 1.0049x over previous
//
#include <hip/hip_runtime.h>
#include <stdint.h>

#define SEQ   1024
#define BATCH 32
#define HID   512
#define G3    1536
#define NW    32          // rec workgroups per direction
#define JPW   16          // hidden units owned per rec WG
#define THREADS 384       // 6 waves (g 0..2) x (mi 0..1) -- proven R0 structure
#define FSTR  256         // flag spacing in ints (1KB)
#define CSTR  64          // prodcnt spacing in ints (256B)
#define CH    16          // steps per Xi chunk
#define NCH   64          // chunks per layer (CH*NCH == SEQ)
#define NG    192         // gate-row groups of 16 (= 3072/16), ng = dir*96+g*32+wg
#define NPROD 192         // producer WGs
#define SPIN_MAX 65536    // spin bail-out; legit waits <<100us (proven neutral R5-R7)

typedef __attribute__((ext_vector_type(8))) short  short8;
typedef __attribute__((ext_vector_type(4))) float  f32x4;
typedef __attribute__((ext_vector_type(4))) unsigned short us4;
typedef unsigned long long ull;

__device__ __forceinline__ unsigned short f2bf(float f) {
  union { float f; unsigned int u; } v; v.f = f;
  unsigned int u = v.u;
  return (unsigned short)((u + 0x7FFFu + ((u >> 16) & 1u)) >> 16);
}
__device__ __forceinline__ float bf2f(unsigned short u) {
  union { unsigned int i; float f; } v; v.i = ((unsigned int)u) << 16; return v.f;
}
__device__ __forceinline__ short8 pack8(const float* __restrict__ p) {
  short8 o;
#pragma unroll
  for (int i = 0; i < 8; i++) o[i] = (short)f2bf(p[i]);
  return o;
}
__device__ __forceinline__ f32x4 mfma16(short8 a, short8 b, f32x4 c) {
  return __builtin_amdgcn_mfma_f32_16x16x32_bf16(a, b, c, 0, 0, 0);
}

// fp32 W [3072][K] -> bf16 B-fragment chunks [ng][kc][64 lane] x 16B
__global__ void cvt_wb(const float* __restrict__ w, short8* __restrict__ out, int kcx, int nc) {
  int c = blockIdx.x * blockDim.x + threadIdx.x;
  if (c >= nc) return;
  int lane = c & 63, r = c >> 6;     // r = ng*kcx + kc
  int kc = r % kcx, ng = r / kcx;
  int n   = ng * 16 + (lane & 15);
  int col = kc * 32 + (lane >> 4) * 8;
  int K = kcx * 32;
  out[c] = pack8(w + (size_t)n * K + col);
}

// One dispatch per layer, grid=256: blocks 0..63 = recurrence (dir=blk>>5,
// wg=blk&31); blocks 64..255 = 192 producers (R0 grouping).
// R7-proven base (coalesced publish via LDS staging) + safe RT shavings:
//  (1) 2-deep pipelined flag poll (two gathers in flight, alternate vmcnt(1));
//      R8's corruption was the rule-#18 hazard -- hipcc hoisted the register
//      comparison above the SEPARATE vmcnt asm. Fixed: sched_barrier(0)
//      immediately after each vmcnt wait pins the compare after it.
//  (2) prodcnt gate folded into the poll as lane 32 (pure loads, same
//      semantics as the nested check) -- no serial second RT at sl==0.
//  R8's vmcnt(1) h-only publish drain is REVERTED (in-order vmcnt retirement
//  is only load-verified; mixed-store ordering unproven): vmcnt(0) drains
//  h+y before the flag, R7-exact.
template<int KCX, bool WRITE_Y>
__global__ __launch_bounds__(THREADS, 1) void gru_mega(
    const void* __restrict__ Ain,      // KCX==8: fp32 x [T][32][256]; else short8 [T][2][KCX][64]
    short8* __restrict__ yout,         // [T][2][32][64] chunks (or null)
    const short8* __restrict__ wb,     // [NG][KCX][64] B-fragments
    const float* __restrict__ whh,     // [2][G3][HID]
    const float* __restrict__ bih,     // [3072]
    const float* __restrict__ bhh,     // [3072]
    us4* __restrict__ Xic,             // [2 slot][CH][NG][2 mi][64]
    short8* __restrict__ hbuf,         // [2 dir][2 par][2 mi][16 kc][64] chunks
    int* __restrict__ flags,           // [2][NW][FSTR]
    int* __restrict__ prodcnt,         // [NCH][CSTR]
    float* __restrict__ hout)          // [2][BATCH][HID] slice of d_out
{
  __shared__ float gbuf[4 * 512];        // [4][32][16] preactivations
  __shared__ float hold[512];            // [32][16] fp32 state
  __shared__ unsigned int sbuf[256];     // 1KB publish staging, global-layout order

  const int tid  = threadIdx.x;
  const int lane = tid & 63;
  const int wave = tid >> 6;
  const int quad = lane >> 4;
  const int l15  = lane & 15;

  if (blockIdx.x >= 64) {
    // ================= producer (R0 grouping) =================
    const int p    = blockIdx.x - 64;  // 0..191
    const int tg   = p & 15;           // sl within chunk (CH==16)
    const int ngg  = p >> 4;           // 0..11 -> ng range [ngg*16, ngg*16+16)
    const int dirp = (ngg >= 6) ? 1 : 0;
    int* fl = flags + dirp * NW * FSTR;

    for (int c = 0; c < NCH; c++) {
      const int tgt = (c >= 2) ? CH * (c - 1) : 0;   // slot free when dirp rec flags >= tgt
      if (wave == 0) {
        int it = 0;
        while (true) {
          int v = (lane < NW)
                    ? __hip_atomic_load(&fl[lane * FSTR], __ATOMIC_RELAXED, __HIP_MEMORY_SCOPE_AGENT)
                    : tgt;
          if (__all(v >= tgt)) break;
          if (++it > SPIN_MAX) break;            // insurance against hangs
          __builtin_amdgcn_s_sleep(4);
        }
      }
      __syncthreads();
      const int sl = tg;
      const int s  = c * CH + sl;
      const int t  = dirp ? (SEQ - 1 - s) : s;
      for (int mi = 0; mi < 2; mi++) {
        short8 a[KCX];
        if constexpr (KCX == 8) {
          const float* xr = (const float*)Ain + ((size_t)t * 32 + mi * 16 + l15) * 256 + quad * 8;
#pragma unroll
          for (int kc = 0; kc < KCX; kc++) a[kc] = pack8(xr + kc * 32);
        } else {
          const short8* ap = (const short8*)Ain + ((size_t)(t * 2 + mi) * KCX) * 64 + lane;
#pragma unroll
          for (int kc = 0; kc < KCX; kc++) a[kc] = ap[kc * 64];
        }
        for (int ng = ngg * 16 + wave; ng < ngg * 16 + 16; ng += 6) {
          const short8* bp = wb + (size_t)ng * KCX * 64 + lane;
          f32x4 ac0 = (f32x4){0.f, 0.f, 0.f, 0.f};
          f32x4 ac1 = (f32x4){0.f, 0.f, 0.f, 0.f};
#pragma unroll
          for (int kc = 0; kc < KCX; kc += 2) {
            ac0 = mfma16(a[kc],     bp[kc * 64],       ac0);
            ac1 = mfma16(a[kc + 1], bp[(kc + 1) * 64], ac1);
          }
          const int n  = ng * 16 + l15;
          const int gg = (ng % 96) >> 5;                    // 0=r,1=z,2=n
          const float bias = bih[n] + (gg < 2 ? bhh[n] : 0.f);
          us4 o;
#pragma unroll
          for (int r = 0; r < 4; r++) o[r] = f2bf(ac0[r] + ac1[r] + bias);
          us4* dst = Xic + ((((size_t)(c & 1)) * CH + sl) * NG + ng) * 128 + mi * 64 + lane;
          asm volatile("global_store_dwordx2 %0, %1, off sc0 sc1" :: "v"(dst), "v"(o) : "memory");
        }
      }
      asm volatile("s_waitcnt vmcnt(0)" ::: "memory");
      __syncthreads();
      if (tid == 0)
        __hip_atomic_fetch_add(&prodcnt[c * CSTR], 1, __ATOMIC_RELAXED, __HIP_MEMORY_SCOPE_AGENT);
    }
    return;
  }

  // ================= recurrence (R7 structure + fixed poll) ============
  const int mi  = wave & 1;
  const int g   = wave >> 1;
  const int dir = blockIdx.x >> 5;
  const int wg  = blockIdx.x & 31;
  const int j0  = wg * JPW;
  const bool rev = (dir == 1);
  const int ngR = dir * 96 + g * 32 + wg;

  short8 wh[16];
  {
    const float* pw = whh + (size_t)dir * G3 * HID + (size_t)(g * HID + j0 + l15) * HID + quad * 8;
#pragma unroll
    for (int kc = 0; kc < 16; kc++) wh[kc] = pack8(pw + kc * 32);
  }
  const float bh = bhh[dir * G3 + g * HID + j0 + l15];

  for (int idx = tid; idx < 512; idx += THREADS) hold[idx] = 0.f;
  __syncthreads();

  int* fl = flags + dir * NW * FSTR;
  char* hb = (char*)(hbuf + (size_t)dir * 2 * 2048);   // [2 par][32KB]

  for (int s = 0; s < SEQ; s++) {
    const int t  = rev ? (SEQ - 1 - s) : s;
    const int c  = s >> 4;
    const int sl = s & 15;

    const char* xp = (const char*)Xic
        + (((((size_t)(c & 1)) * CH + sl) * NG + ngR) * 128 + mi * 64 + lane) * 8;
    ull xi64 = 0;
    if (sl != 0)   // chunk validated at its sl==0 step: pre-spin load overlaps the wait
      asm volatile("global_load_dwordx2 %0, %1, off sc0 sc1\n\ts_waitcnt vmcnt(0)"
                   : "=v"(xi64) : "v"(xp) : "memory");

    if (wave == 0) {
      // per-lane poll target: lanes 0..31 -> per-WG step flags; lane 32 ->
      // prodcnt gate (meaningful at sl==0); others -> always-true dummy.
      const int* pa;
      int tgt;
      if (lane < 32)                  { pa = &fl[lane * FSTR];   tgt = s; }
      else if (lane == 32 && sl == 0) { pa = &prodcnt[c * CSTR]; tgt = NPROD; }
      else                            { pa = &fl[0];             tgt = (int)0x80000001; }
      int v0, v1;
      int it = 0;
      asm volatile("global_load_dword %0, %1, off sc0 sc1" : "=v"(v0) : "v"(pa) : "memory");
      while (true) {
        asm volatile("global_load_dword %0, %1, off sc0 sc1" : "=v"(v1) : "v"(pa) : "memory");
        asm volatile("s_waitcnt vmcnt(1)" ::: "memory");      // v0 landed
        __builtin_amdgcn_sched_barrier(0);                    // rule #18: pin compare after wait
        if (__all(v0 >= tgt)) break;
        if (++it > SPIN_MAX) break;
        asm volatile("global_load_dword %0, %1, off sc0 sc1" : "=v"(v0) : "v"(pa) : "memory");
        asm volatile("s_waitcnt vmcnt(1)" ::: "memory");      // v1 landed
        __builtin_amdgcn_sched_barrier(0);
        if (__all(v1 >= tgt)) break;
        if (++it > SPIN_MAX) break;
      }
      asm volatile("s_waitcnt vmcnt(0)" ::: "memory");        // quiesce dangling poll
      __builtin_amdgcn_sched_barrier(0);
    }
    __syncthreads();
    if (sl == 0)   // slot only valid after the prodcnt gate
      asm volatile("global_load_dwordx2 %0, %1, off sc0 sc1\n\ts_waitcnt vmcnt(0)"
                   : "=v"(xi64) : "v"(xp) : "memory");

    f32x4 p0 = (f32x4){0.f, 0.f, 0.f, 0.f};
    f32x4 p1 = (f32x4){0.f, 0.f, 0.f, 0.f};

    if (s > 0) {
      const char* hp = hb + (size_t)((s - 1) & 1) * 32768 + (size_t)mi * 16384 + (size_t)lane * 16;
      short8 a0, a1, a2, a3, a4, a5, a6, a7, a8, a9, a10, a11, a12, a13, a14, a15;
      asm volatile(
          "global_load_dwordx4 %0, %16, off sc0 sc1\n\t"
          "global_load_dwordx4 %1, %16, off offset:1024 sc0 sc1\n\t"
          "global_load_dwordx4 %2, %16, off offset:2048 sc0 sc1\n\t"
          "global_load_dwordx4 %3, %16, off offset:3072 sc0 sc1\n\t"
          "global_load_dwordx4 %4, %17, off sc0 sc1\n\t"
          "global_load_dwordx4 %5, %17, off offset:1024 sc0 sc1\n\t"
          "global_load_dwordx4 %6, %17, off offset:2048 sc0 sc1\n\t"
          "global_load_dwordx4 %7, %17, off offset:3072 sc0 sc1\n\t"
          "global_load_dwordx4 %8, %18, off sc0 sc1\n\t"
          "global_load_dwordx4 %9, %18, off offset:1024 sc0 sc1\n\t"
          "global_load_dwordx4 %10, %18, off offset:2048 sc0 sc1\n\t"
          "global_load_dwordx4 %11, %18, off offset:3072 sc0 sc1\n\t"
          "global_load_dwordx4 %12, %19, off sc0 sc1\n\t"
          "global_load_dwordx4 %13, %19, off offset:1024 sc0 sc1\n\t"
          "global_load_dwordx4 %14, %19, off offset:2048 sc0 sc1\n\t"
          "global_load_dwordx4 %15, %19, off offset:3072 sc0 sc1\n\t"
          "s_waitcnt vmcnt(0)"
          : "=&v"(a0), "=&v"(a1), "=&v"(a2), "=&v"(a3),
            "=&v"(a4), "=&v"(a5), "=&v"(a6), "=&v"(a7),
            "=&v"(a8), "=&v"(a9), "=&v"(a10), "=&v"(a11),
            "=&v"(a12), "=&v"(a13), "=&v"(a14), "=&v"(a15)
          : "v"(hp), "v"(hp + 4096), "v"(hp + 8192), "v"(hp + 12288)
          : "memory");
      p0 = mfma16(a0,  wh[0],  p0);
      p1 = mfma16(a1,  wh[1],  p1);
      p0 = mfma16(a2,  wh[2],  p0);
      p1 = mfma16(a3,  wh[3],  p1);
      p0 = mfma16(a4,  wh[4],  p0);
      p1 = mfma16(a5,  wh[5],  p1);
      p0 = mfma16(a6,  wh[6],  p0);
      p1 = mfma16(a7,  wh[7],  p1);
      p0 = mfma16(a8,  wh[8],  p0);
      p1 = mfma16(a9,  wh[9],  p1);
      p0 = mfma16(a10, wh[10], p0);
      p1 = mfma16(a11, wh[11], p1);
      p0 = mfma16(a12, wh[12], p0);
      p1 = mfma16(a13, wh[13], p1);
      p0 = mfma16(a14, wh[14], p0);
      p1 = mfma16(a15, wh[15], p1);
    }

    // ---- merge Xi + h-projection; dump preactivations (D: m = mi*16+quad*4+r) ----
#pragma unroll
    for (int r = 0; r < 4; r++) {
      int m = mi * 16 + quad * 4 + r;
      float xv = bf2f((unsigned short)(xi64 >> (16 * r)));
      if (g < 2) {
        gbuf[(g * 32 + m) * JPW + l15] = xv + p0[r] + p1[r];
      } else {
        gbuf[(2 * 32 + m) * JPW + l15] = xv;
        gbuf[(3 * 32 + m) * JPW + l15] = bh + p0[r] + p1[r];
      }
    }
    __syncthreads();

    // ---- gates + state: threads 0..255, 2 elems each; stage publish in LDS ----
    if (tid < 256) {
      int b = tid >> 3, jj = tid & 7;
      int e0 = b * 16 + 2 * jj;
      float h2[2];
#pragma unroll
      for (int e = 0; e < 2; e++) {
        int idx = e0 + e;
        int j = (idx & 15);
        float pr = gbuf[(0 * 32 + b) * JPW + j];
        float pz = gbuf[(1 * 32 + b) * JPW + j];
        float px = gbuf[(2 * 32 + b) * JPW + j];
        float ph = gbuf[(3 * 32 + b) * JPW + j];
        float rr = 1.f / (1.f + __expf(-pr));
        float zz = 1.f / (1.f + __expf(-pz));
        float a2 = px + rr * ph;
        float ex = __expf(2.f * a2);
        float nn = 1.f - 2.f / (ex + 1.f);        // tanh(a2)
        float hp2 = hold[idx];
        float hnew = (1.f - zz) * nn + zz * hp2;
        hold[idx] = hnew;
        h2[e] = hnew;
      }
      unsigned int val = (unsigned int)f2bf(h2[0]) | ((unsigned int)f2bf(h2[1]) << 16);
      // stage in global-layout order: [mi=b>>4][granule gl=(b&15)+(jj>>2)*16][dword jj&3]
      sbuf[(b >> 4) * 128 + ((b & 15) + (jj >> 2) * 16) * 4 + (jj & 3)] = val;
      if (s == SEQ - 1) {
        int k = j0 + 2 * jj;
        hout[((size_t)dir * 32 + b) * HID + k]     = h2[0];
        hout[((size_t)dir * 32 + b) * HID + k + 1] = h2[1];
      }
    }
    __syncthreads();   // sbuf ready

    // ---- coalesced publish + flag: wave 0 only (others flow to next spin) ----
    if (wave == 0) {
      const int lm  = lane >> 5;          // mi half
      const int l31 = lane & 31;          // granule within the WG's 512B region
      f32x4 v = *(f32x4*)((char*)sbuf + (size_t)lane * 16);
      char* hdst = hb + (size_t)(s & 1) * 32768 + (size_t)lm * 16384
                 + (size_t)wg * 512 + (size_t)l31 * 16;
      asm volatile("global_store_dwordx4 %0, %1, off sc0 sc1" :: "v"(hdst), "v"(v) : "memory");
      if (WRITE_Y) {
        char* ydst = (char*)yout
            + (((size_t)(t * 2 + lm) * 32 + (dir << 4)) * 64) * 16
            + (size_t)wg * 512 + (size_t)l31 * 16;
        asm volatile("global_store_dwordx4 %0, %1, off" :: "v"(ydst), "v"(v) : "memory");
      }
      asm volatile("s_waitcnt vmcnt(0)" ::: "memory");   // drain h (and y) before flag
      if (tid == 0)
        __hip_atomic_store(&fl[wg * FSTR], s + 1, __ATOMIC_RELAXED, __HIP_MEMORY_SCOPE_AGENT);
    }
    // no barrier here: the next iteration's post-spin __syncthreads resyncs,
    // and no thread touches gbuf/hold/sbuf before passing it.
  }
}

extern "C" void kernel_launch(void* const* d_in, const int* in_sizes, int n_in,
                              void* d_out, int out_size, void* d_ws, size_t ws_size,
                              hipStream_t stream)
{
  const float* x       = (const float*)d_in[0];
  const float* w_ih_l0 = (const float*)d_in[1];
  const float* w_hh_l0 = (const float*)d_in[2];
  const float* b_ih_l0 = (const float*)d_in[3];
  const float* b_hh_l0 = (const float*)d_in[4];
  const float* w_ih_lr = (const float*)d_in[5];
  const float* w_hh_lr = (const float*)d_in[6];
  const float* b_ih_lr = (const float*)d_in[7];
  const float* b_hh_lr = (const float*)d_in[8];
  float* out = (float*)d_out;

  char* ws = (char*)d_ws;
  size_t off = 0;
  auto alloc = [&](size_t bytes) {
    char* p = ws + off;
    off += (bytes + 255) & ~(size_t)255;
    return p;
  };
  short8* y0   = (short8*)alloc((size_t)SEQ * 2 * 32 * 64 * 16);   // 64 MB
  short8* y1   = (short8*)alloc((size_t)SEQ * 2 * 32 * 64 * 16);   // 64 MB
  short8* wb   = (short8*)alloc((size_t)NG * 32 * 64 * 16);        // 6 MB
  short8* hbuf = (short8*)alloc((size_t)2 * 2 * 2048 * 16);        // 128 KB
  int*    flags   = (int*)alloc((size_t)3 * 2 * NW * FSTR * 4);    // 192 KB
  int*    prodcnt = (int*)alloc((size_t)3 * NCH * CSTR * 4);       // 48 KB
  us4*    Xic  = (us4*)alloc((size_t)2 * CH * NG * 2 * 64 * 8);    // 6 MB
  // total ~140.4 MiB < proven-safe 151 MB

  hipMemsetAsync(flags, 0, (size_t)3 * 2 * NW * FSTR * 4, stream);
  hipMemsetAsync(prodcnt, 0, (size_t)3 * NCH * CSTR * 4, stream);

  // ---- layer 0 (K=256, fp32 x read directly by producers) ----
  {
    int nc = NG * 8 * 64;
    cvt_wb<<<(nc + 255) / 256, 256, 0, stream>>>(w_ih_l0, wb, 8, nc);
    gru_mega<8, true><<<256, THREADS, 0, stream>>>(
        x, y0, wb, w_hh_l0, b_ih_l0, b_hh_l0, Xic, hbuf, flags, prodcnt, out);
  }
  // ---- layer 1 ----
  {
    int nc = NG * 32 * 64;
    cvt_wb<<<(nc + 255) / 256, 256, 0, stream>>>(w_ih_lr, wb, 32, nc);
    gru_mega<32, true><<<256, THREADS, 0, stream>>>(
        y0, y1, wb, w_hh_lr, b_ih_lr, b_hh_lr, Xic, hbuf,
        flags + 2 * NW * FSTR, prodcnt + NCH * CSTR, out + 2 * BATCH * HID);
  }
  // ---- layer 2 ----
  {
    int nc = NG * 32 * 64;
    cvt_wb<<<(nc + 255) / 256, 256, 0, stream>>>(w_ih_lr + (size_t)2 * G3 * 1024, wb, 32, nc);
    gru_mega<32, false><<<256, THREADS, 0, stream>>>(
        y1, nullptr, wb, w_hh_lr + (size_t)2 * G3 * HID,
        b_ih_lr + 2 * G3, b_hh_lr + 2 * G3, Xic, hbuf,
        flags + 4 * NW * FSTR, prodcnt + 2 * NCH * CSTR, out + 4 * BATCH * HID);
  }
}